// Round 2
// baseline (2138.850 us; speedup 1.0000x reference)
//
#include <hip/hip_runtime.h>
#include <math.h>

#define B_ 4
#define L_ 4096
#define D_ 1024
#define DG_ 256
#define NC_ 64          // number of chunks along L
#define CL_ 64          // chunk length (L_/NC_)
#define PI_F 3.14159265358979323846f
#define LN_EPS_F 1e-5f

typedef _Float16 half_t;
typedef _Float16 h4_t __attribute__((ext_vector_type(4)));

__device__ inline float4 ld4f(const float* p) { return *reinterpret_cast<const float4*>(p); }
__device__ inline float4 ld4f(const half_t* p) {
    h4_t v = *reinterpret_cast<const h4_t*>(p);
    return make_float4((float)v[0], (float)v[1], (float)v[2], (float)v[3]);
}
__device__ inline void st1(float* p, float v)  { *p = v; }
__device__ inline void st1(half_t* p, float v) { *p = (half_t)v; }

// ---------------------------------------------------------------------------
// Tiled fp32-compute GEMM with fused epilogue.
//   out[M,N] = epi( A[M,K] @ W[K,N] + bias[N] )
// EPI: 0 = none, 1 = tanh(c)*pi, 2 = gelu(tanh approx), 3 = c + X[m,n]
// ---------------------------------------------------------------------------
template<typename AT, typename OT, int EPI>
__global__ __launch_bounds__(256)
void gemm_epi(const AT* __restrict__ A, const float* __restrict__ W,
              const float* __restrict__ bias, const float* __restrict__ X,
              OT* __restrict__ out, int M, int N, int K)
{
    __shared__ float As[16][64];   // [k][m]
    __shared__ float Bs[16][64];   // [k][n]

    const int tid = threadIdx.x;
    const int bm = blockIdx.y * 64;
    const int bn = blockIdx.x * 64;
    const int tx = tid & 15;   // -> n
    const int ty = tid >> 4;   // -> m

    const int la_row = tid >> 2;         // 0..63 (m within tile)
    const int la_k4  = (tid & 3) * 4;    // 0,4,8,12
    const int lb_row = tid >> 4;         // 0..15 (k within tile)
    const int lb_c4  = (tid & 15) * 4;   // n within tile

    float acc[4][4] = {};

    for (int k0 = 0; k0 < K; k0 += 16) {
        float4 av = ld4f(&A[(size_t)(bm + la_row) * K + k0 + la_k4]);
        As[la_k4 + 0][la_row] = av.x;
        As[la_k4 + 1][la_row] = av.y;
        As[la_k4 + 2][la_row] = av.z;
        As[la_k4 + 3][la_row] = av.w;
        float4 wv = ld4f(&W[(size_t)(k0 + lb_row) * N + bn + lb_c4]);
        *reinterpret_cast<float4*>(&Bs[lb_row][lb_c4]) = wv;
        __syncthreads();

        #pragma unroll
        for (int k = 0; k < 16; ++k) {
            float4 a4 = *reinterpret_cast<const float4*>(&As[k][ty * 4]);
            float4 b4 = *reinterpret_cast<const float4*>(&Bs[k][tx * 4]);
            float av_[4] = {a4.x, a4.y, a4.z, a4.w};
            float bv_[4] = {b4.x, b4.y, b4.z, b4.w};
            #pragma unroll
            for (int i = 0; i < 4; ++i)
                #pragma unroll
                for (int j = 0; j < 4; ++j)
                    acc[i][j] += av_[i] * bv_[j];
        }
        __syncthreads();
    }

    #pragma unroll
    for (int i = 0; i < 4; ++i) {
        const int m = bm + ty * 4 + i;
        #pragma unroll
        for (int j = 0; j < 4; ++j) {
            const int n = bn + tx * 4 + j;
            float c = acc[i][j] + bias[n];
            if constexpr (EPI == 1) {
                c = tanhf(c) * PI_F;
            } else if constexpr (EPI == 2) {
                float t = 0.7978845608028654f * (c + 0.044715f * c * c * c);
                c = 0.5f * c * (1.0f + tanhf(t));
            } else if constexpr (EPI == 3) {
                c += X[(size_t)m * N + n];
            }
            st1(&out[(size_t)m * N + n], c);
        }
    }
}

// ---------------------------------------------------------------------------
// gate[row] = sigmoid( H[row,:] . Wg2 + bg2 ),  row in [0, B*L)
// ---------------------------------------------------------------------------
__global__ __launch_bounds__(256)
void gate_kernel(const half_t* __restrict__ H, const float* __restrict__ Wg2,
                 const float* __restrict__ bg2, float* __restrict__ gate)
{
    const int wid = threadIdx.x >> 6;
    const int lane = threadIdx.x & 63;
    const int row = blockIdx.x * 4 + wid;
    float4 h = ld4f(&H[(size_t)row * DG_ + lane * 4]);
    float4 w = ld4f(&Wg2[lane * 4]);
    float s = h.x * w.x + h.y * w.y + h.z * w.z + h.w * w.w;
    #pragma unroll
    for (int o = 32; o; o >>= 1) s += __shfl_down(s, o);
    if (lane == 0) gate[row] = 1.0f / (1.0f + expf(-(s + bg2[0])));
}

// ---------------------------------------------------------------------------
// Pass A: per-chunk sums of V*cos(kp), V*sin(kp), V*cos(pp), V*sin(pp)
// ---------------------------------------------------------------------------
__global__ __launch_bounds__(256)
void passA(const half_t* __restrict__ V, const half_t* __restrict__ KP,
           const float* __restrict__ PP, float* __restrict__ Scr,
           float* __restrict__ Sci, float* __restrict__ Spr,
           float* __restrict__ Spi)
{
    const int bid = blockIdx.x;
    const int b = bid >> 8;
    const int rem = bid & 255;
    const int c = rem >> 2;
    const int d = (rem & 3) * 256 + threadIdx.x;

    float cr = 0.f, ci = 0.f, pr = 0.f, pi = 0.f;
    const size_t base = ((size_t)b * L_ + (size_t)c * CL_) * D_ + d;
    const size_t pbase = (size_t)c * CL_ * D_ + d;
    for (int l = 0; l < CL_; ++l) {
        float v  = (float)V[base + (size_t)l * D_];
        float kp = (float)KP[base + (size_t)l * D_];
        float pp = PP[pbase + (size_t)l * D_];
        float sk, ck, sp, cp;
        sincosf(kp, &sk, &ck);
        sincosf(pp, &sp, &cp);
        cr += v * ck; ci += v * sk;
        pr += v * cp; pi += v * sp;
    }
    const size_t sidx = ((size_t)b * NC_ + c) * D_ + d;
    Scr[sidx] = cr; Sci[sidx] = ci; Spr[sidx] = pr; Spi[sidx] = pi;
}

// ---------------------------------------------------------------------------
// Pass B: in-place exclusive scan over chunks, per (b,d)
// ---------------------------------------------------------------------------
__global__ __launch_bounds__(256)
void passB(float* __restrict__ Scr, float* __restrict__ Sci,
           float* __restrict__ Spr, float* __restrict__ Spi)
{
    const int idx = blockIdx.x * 256 + threadIdx.x;  // 0..B*D-1
    const int b = idx >> 10;
    const int d = idx & 1023;
    float rcr = 0.f, rci = 0.f, rpr = 0.f, rpi = 0.f;
    for (int c = 0; c < NC_; ++c) {
        const size_t s = ((size_t)b * NC_ + c) * D_ + d;
        float t;
        t = Scr[s]; Scr[s] = rcr; rcr += t;
        t = Sci[s]; Sci[s] = rci; rci += t;
        t = Spr[s]; Spr[s] = rpr; rpr += t;
        t = Spi[s]; Spi[s] = rpi; rpi += t;
    }
}

// ---------------------------------------------------------------------------
// Pass C: replay scan, combine with gate, /sqrt(pos), fused LayerNorm over D
// ---------------------------------------------------------------------------
__global__ __launch_bounds__(1024)
void passC(const half_t* __restrict__ V, const half_t* __restrict__ KP,
           const half_t* __restrict__ QP, const float* __restrict__ PP,
           const float* __restrict__ gate, const float* __restrict__ Scr,
           const float* __restrict__ Sci, const float* __restrict__ Spr,
           const float* __restrict__ Spi, const float* __restrict__ ln_g,
           const float* __restrict__ ln_b, half_t* __restrict__ Y)
{
    const int bid = blockIdx.x;
    const int b = bid >> 6;     // / NC_
    const int c = bid & 63;
    const int d = threadIdx.x;

    const size_t sidx = ((size_t)b * NC_ + c) * D_ + d;
    float cr = Scr[sidx], ci = Sci[sidx], pr = Spr[sidx], pi = Spi[sidx];
    const float g_ln = ln_g[d];
    const float b_ln = ln_b[d];

    __shared__ float2 lred[16];
    const int wid = threadIdx.x >> 6;
    const int lane = threadIdx.x & 63;

    for (int l0 = 0; l0 < CL_; ++l0) {
        const int l = c * CL_ + l0;
        const size_t off = ((size_t)b * L_ + l) * D_ + d;
        float v  = (float)V[off];
        float kp = (float)KP[off];
        float qp = (float)QP[off];
        float pp = PP[(size_t)l * D_ + d];
        float gv = gate[b * L_ + l];

        float sk, ck, sq, cq, sp, cp;
        sincosf(kp, &sk, &ck);
        sincosf(qp, &sq, &cq);
        sincosf(pp, &sp, &cp);

        cr += v * ck; ci += v * sk;
        pr += v * cp; pi += v * sp;

        float content = cr * cq + ci * sq;
        float posr    = pr * cp + pi * sp;
        float comb    = gv * content + (1.0f - gv) * posr;
        float u       = comb * rsqrtf((float)(l + 1));

        float s = u, s2 = u * u;
        #pragma unroll
        for (int o = 32; o; o >>= 1) {
            s  += __shfl_down(s, o);
            s2 += __shfl_down(s2, o);
        }
        if (lane == 0) lred[wid] = make_float2(s, s2);
        __syncthreads();
        float ts = 0.f, ts2 = 0.f;
        #pragma unroll
        for (int i = 0; i < 16; ++i) { ts += lred[i].x; ts2 += lred[i].y; }
        const float mu  = ts * (1.0f / D_);
        const float var = ts2 * (1.0f / D_) - mu * mu;
        const float y = (u - mu) * rsqrtf(var + LN_EPS_F) * g_ln + b_ln;
        st1(&Y[off], y);
        __syncthreads();
    }
}

// ---------------------------------------------------------------------------
extern "C" void kernel_launch(void* const* d_in, const int* in_sizes, int n_in,
                              void* d_out, int out_size, void* d_ws, size_t ws_size,
                              hipStream_t stream)
{
    const float* x    = (const float*)d_in[0];
    const float* Wk   = (const float*)d_in[1];
    const float* bk   = (const float*)d_in[2];
    const float* Wq   = (const float*)d_in[3];
    const float* bq   = (const float*)d_in[4];
    const float* Wv   = (const float*)d_in[5];
    const float* bv   = (const float*)d_in[6];
    const float* ln_g = (const float*)d_in[7];
    const float* ln_b = (const float*)d_in[8];
    const float* Wo   = (const float*)d_in[9];
    const float* bo   = (const float*)d_in[10];
    const float* Wg1  = (const float*)d_in[11];
    const float* bg1  = (const float*)d_in[12];
    const float* Wg2  = (const float*)d_in[13];
    const float* bg2  = (const float*)d_in[14];
    const float* PP   = (const float*)d_in[15];

    float* out = (float*)d_out;

    const size_t BLD = (size_t)B_ * L_ * D_;

    // Workspace layout (bytes):
    //   KP, QP, V, Y : fp16, BLD each            = 4 * 32 MB
    //   H            : fp16, B*L*DG              = 8 MB
    //   gate         : fp32, B*L                 = 64 KB
    //   Scr/Sci/Spr/Spi : fp32, B*NC*D each      = 4 * 1 MB
    const size_t NEED = BLD * 2 * 4             // KP QP V Y
                      + (size_t)B_ * L_ * DG_ * 2
                      + (size_t)B_ * L_ * 4
                      + (size_t)B_ * NC_ * D_ * 4 * 4;
    if (ws_size < NEED) {
        // Diagnostic fallback: clean absmax failure (~max|out-x|) instead of a
        // memory-fault crash. Tells us ws_size is the binding constraint.
        hipMemcpyAsync(d_out, d_in[0], BLD * sizeof(float),
                       hipMemcpyDeviceToDevice, stream);
        return;
    }

    char* wsb = (char*)d_ws;
    half_t* KP   = (half_t*)wsb;                     wsb += BLD * 2;
    half_t* QP   = (half_t*)wsb;                     wsb += BLD * 2;
    half_t* V    = (half_t*)wsb;                     wsb += BLD * 2;
    half_t* Y    = (half_t*)wsb;                     wsb += BLD * 2;
    half_t* H    = (half_t*)wsb;                     wsb += (size_t)B_ * L_ * DG_ * 2;
    float*  gate = (float*)wsb;                      wsb += (size_t)B_ * L_ * 4;
    float*  Scr  = (float*)wsb;                      wsb += (size_t)B_ * NC_ * D_ * 4;
    float*  Sci  = (float*)wsb;                      wsb += (size_t)B_ * NC_ * D_ * 4;
    float*  Spr  = (float*)wsb;                      wsb += (size_t)B_ * NC_ * D_ * 4;
    float*  Spi  = (float*)wsb;

    const int M = B_ * L_;
    dim3 blk(256);
    dim3 gD(D_ / 64, M / 64);
    dim3 gG(DG_ / 64, M / 64);

    hipLaunchKernelGGL((gemm_epi<float, half_t, 1>), gD, blk, 0, stream,
                       x, Wk, bk, nullptr, KP, M, D_, D_);
    hipLaunchKernelGGL((gemm_epi<float, half_t, 1>), gD, blk, 0, stream,
                       x, Wq, bq, nullptr, QP, M, D_, D_);
    hipLaunchKernelGGL((gemm_epi<float, half_t, 0>), gD, blk, 0, stream,
                       x, Wv, bv, nullptr, V, M, D_, D_);
    hipLaunchKernelGGL((gemm_epi<float, half_t, 2>), gG, blk, 0, stream,
                       x, Wg1, bg1, nullptr, H, M, DG_, D_);

    gate_kernel<<<M / 4, 256, 0, stream>>>(H, Wg2, bg2, gate);

    passA<<<B_ * NC_ * 4, 256, 0, stream>>>(V, KP, PP, Scr, Sci, Spr, Spi);
    passB<<<(B_ * D_) / 256, 256, 0, stream>>>(Scr, Sci, Spr, Spi);
    passC<<<B_ * NC_, 1024, 0, stream>>>(V, KP, QP, PP, gate, Scr, Sci, Spr, Spi,
                                         ln_g, ln_b, Y);

    hipLaunchKernelGGL((gemm_epi<half_t, float, 3>), gD, blk, 0, stream,
                       Y, Wo, bo, x, out, M, D_, D_);
}

// Round 3
// 593.793 us; speedup vs baseline: 3.6020x; 3.6020x over previous
//
#include <hip/hip_runtime.h>
#include <math.h>

#define B_ 4
#define L_ 4096
#define D_ 1024
#define DG_ 256
#define NC_ 64          // number of chunks along L
#define CL_ 64          // chunk length (L_/NC_)
#define PI_F 3.14159265358979323846f
#define LN_EPS_F 1e-5f

typedef __attribute__((ext_vector_type(8))) short bf16x8;
typedef __attribute__((ext_vector_type(4))) short s16x4;
typedef __attribute__((ext_vector_type(4))) float f32x4;

// ---- dtype helpers (all fp16/bf16 stored as bit-patterns in short arrays) ----
__device__ inline short f2bf(float f) {
    unsigned u = __builtin_bit_cast(unsigned, f);
    u += 0x7FFFu + ((u >> 16) & 1u);          // round-to-nearest-even
    return (short)(u >> 16);
}
__device__ inline float bf2f(short s) {
    unsigned u = ((unsigned)(unsigned short)s) << 16;
    return __builtin_bit_cast(float, u);
}
__device__ inline short f2h(float f) { return __builtin_bit_cast(short, (_Float16)f); }
__device__ inline float h2f(short s) { return (float)__builtin_bit_cast(_Float16, s); }

__device__ inline void gld16(const void* g, void* l) {
    __builtin_amdgcn_global_load_lds(
        (const __attribute__((address_space(1))) unsigned int*)g,
        (__attribute__((address_space(3))) unsigned int*)l, 16, 0, 0);
}

// ---------------------------------------------------------------------------
// conv_x: fp32 -> bf16, 8 elems/thread
// ---------------------------------------------------------------------------
__global__ __launch_bounds__(256)
void conv_x(const float* __restrict__ x, short* __restrict__ xh, int n8)
{
    int t = blockIdx.x * 256 + threadIdx.x;
    if (t >= n8) return;
    const float4* p = (const float4*)x + (size_t)t * 2;
    float4 a = p[0], b = p[1];
    bf16x8 v;
    v[0] = f2bf(a.x); v[1] = f2bf(a.y); v[2] = f2bf(a.z); v[3] = f2bf(a.w);
    v[4] = f2bf(b.x); v[5] = f2bf(b.y); v[6] = f2bf(b.z); v[7] = f2bf(b.w);
    *(bf16x8*)(xh + (size_t)t * 8) = v;
}

// ---------------------------------------------------------------------------
// convT: W[1024][N] fp32 -> Th[N][1024] bf16 (optionally + Tl residual bf16)
// uncoalesced reads but matrices fit L2; runs once, cheap.
// ---------------------------------------------------------------------------
template<bool SPLIT>
__global__ __launch_bounds__(256)
void convT(const float* __restrict__ W, short* __restrict__ Th,
           short* __restrict__ Tl, int N)
{
    int idx = blockIdx.x * 256 + threadIdx.x;   // over N*1024
    int n = idx >> 10, k = idx & 1023;
    float v = W[(size_t)k * N + n];
    short h = f2bf(v);
    Th[idx] = h;
    if constexpr (SPLIT) Tl[idx] = f2bf(v - bf2f(h));
}

// ---------------------------------------------------------------------------
// MFMA bf16 GEMM, m97 structure: 128x128 tile, BK=32, 4 waves (2x2), 4x4 frags.
//   out[M,N] = epi( A[M,K] @ Bt[N,K]^T + bias[N] )   (Bt = transposed weights)
// SPLITB: acc += A@Bh + A@Bl  (weight hi/lo split for precision)
// EPI: 0 none->fp16, 1 tanh*pi->fp16, 2 gelu->fp16, 3 +X -> fp32
// ---------------------------------------------------------------------------
template<int EPI, bool SPLITB, typename OT>
__global__ __launch_bounds__(256)
void mgemm(const short* __restrict__ A, const short* __restrict__ Bh,
           const short* __restrict__ Bl, const float* __restrict__ bias,
           const float* __restrict__ X, OT* __restrict__ out,
           int M, int N, int K)
{
    __shared__ __align__(16) short As [128 * 32];
    __shared__ __align__(16) short Bsh[128 * 32];
    __shared__ __align__(16) short Bsl[128 * 32];

    const int tid = threadIdx.x;
    const int w  = tid >> 6, l = tid & 63;
    const int wr = w >> 1,  wc = w & 1;
    const int fr = l & 15,  kb = l >> 4;
    const int bm = blockIdx.y * 128, bn = blockIdx.x * 128;

    // staging: wave w stages rows [w*32, w*32+32) of each tile, 2 chunks of 16 rows
    const int srow  = l >> 2;            // row within 16-row chunk
    const int scol  = (l & 3) * 8;       // bf16 elems (16B per lane)
    const short* gA0 = A  + (size_t)(bm + w * 32 +  0 + srow) * K + scol;
    const short* gA1 = A  + (size_t)(bm + w * 32 + 16 + srow) * K + scol;
    const short* gB0 = Bh + (size_t)(bn + w * 32 +  0 + srow) * K + scol;
    const short* gB1 = Bh + (size_t)(bn + w * 32 + 16 + srow) * K + scol;
    const short* gC0 = SPLITB ? Bl + (size_t)(bn + w * 32 +  0 + srow) * K + scol : nullptr;
    const short* gC1 = SPLITB ? Bl + (size_t)(bn + w * 32 + 16 + srow) * K + scol : nullptr;

    short* lA0 = &As [(w * 32 +  0) * 32];
    short* lA1 = &As [(w * 32 + 16) * 32];
    short* lB0 = &Bsh[(w * 32 +  0) * 32];
    short* lB1 = &Bsh[(w * 32 + 16) * 32];
    short* lC0 = &Bsl[(w * 32 +  0) * 32];
    short* lC1 = &Bsl[(w * 32 + 16) * 32];

    f32x4 acc[4][4] = {};

    for (int k0 = 0; k0 < K; k0 += 32) {
        gld16(gA0 + k0, lA0); gld16(gA1 + k0, lA1);
        gld16(gB0 + k0, lB0); gld16(gB1 + k0, lB1);
        if constexpr (SPLITB) { gld16(gC0 + k0, lC0); gld16(gC1 + k0, lC1); }
        __syncthreads();

        bf16x8 af[4], bf[4], cf[4];
        #pragma unroll
        for (int m = 0; m < 4; ++m)
            af[m] = *(const bf16x8*)&As[(wr * 64 + m * 16 + fr) * 32 + kb * 8];
        #pragma unroll
        for (int n = 0; n < 4; ++n) {
            bf[n] = *(const bf16x8*)&Bsh[(wc * 64 + n * 16 + fr) * 32 + kb * 8];
            if constexpr (SPLITB)
                cf[n] = *(const bf16x8*)&Bsl[(wc * 64 + n * 16 + fr) * 32 + kb * 8];
        }
        #pragma unroll
        for (int m = 0; m < 4; ++m)
            #pragma unroll
            for (int n = 0; n < 4; ++n) {
                acc[m][n] = __builtin_amdgcn_mfma_f32_16x16x32_bf16(af[m], bf[n], acc[m][n], 0, 0, 0);
                if constexpr (SPLITB)
                    acc[m][n] = __builtin_amdgcn_mfma_f32_16x16x32_bf16(af[m], cf[n], acc[m][n], 0, 0, 0);
            }
        __syncthreads();
    }

    // epilogue: C/D layout col=lane&15, row=(lane>>4)*4+reg  [guide m89/m91]
    #pragma unroll
    for (int n = 0; n < 4; ++n) {
        const int col = bn + wc * 64 + n * 16 + fr;
        const float bcol = bias[col];
        #pragma unroll
        for (int m = 0; m < 4; ++m) {
            #pragma unroll
            for (int r = 0; r < 4; ++r) {
                const int row = bm + wr * 64 + m * 16 + kb * 4 + r;
                float c = acc[m][n][r] + bcol;
                if constexpr (EPI == 1) {
                    c = tanhf(c) * PI_F;
                } else if constexpr (EPI == 2) {
                    float t = 0.7978845608028654f * (c + 0.044715f * c * c * c);
                    c = 0.5f * c * (1.0f + tanhf(t));
                } else if constexpr (EPI == 3) {
                    c += X[(size_t)row * N + col];
                }
                if constexpr (sizeof(OT) == 2)
                    out[(size_t)row * N + col] = (OT)f2h(c);
                else
                    out[(size_t)row * N + col] = c;
            }
        }
    }
}

// ---------------------------------------------------------------------------
// gate[row] = sigmoid( H[row,:] . Wg2 + bg2 )
// ---------------------------------------------------------------------------
__global__ __launch_bounds__(256)
void gate_kernel(const short* __restrict__ H, const float* __restrict__ Wg2,
                 const float* __restrict__ bg2, float* __restrict__ gate)
{
    const int wid = threadIdx.x >> 6;
    const int lane = threadIdx.x & 63;
    const int row = blockIdx.x * 4 + wid;
    s16x4 hv = *(const s16x4*)&H[(size_t)row * DG_ + lane * 4];
    float4 wv = *(const float4*)&Wg2[lane * 4];
    float s = h2f(hv[0]) * wv.x + h2f(hv[1]) * wv.y + h2f(hv[2]) * wv.z + h2f(hv[3]) * wv.w;
    #pragma unroll
    for (int o = 32; o; o >>= 1) s += __shfl_down(s, o);
    if (lane == 0) gate[row] = 1.0f / (1.0f + expf(-(s + bg2[0])));
}

// ---------------------------------------------------------------------------
// Pass A: per-chunk sums of V*cos(kp), V*sin(kp), V*cos(pp), V*sin(pp)
// ---------------------------------------------------------------------------
__global__ __launch_bounds__(256)
void passA(const short* __restrict__ V, const short* __restrict__ KP,
           const float* __restrict__ PP, float* __restrict__ Scr,
           float* __restrict__ Sci, float* __restrict__ Spr,
           float* __restrict__ Spi)
{
    const int bid = blockIdx.x;
    const int b = bid >> 8;
    const int rem = bid & 255;
    const int c = rem >> 2;
    const int d = (rem & 3) * 256 + threadIdx.x;

    float cr = 0.f, ci = 0.f, pr = 0.f, pi = 0.f;
    const size_t base = ((size_t)b * L_ + (size_t)c * CL_) * D_ + d;
    const size_t pbase = (size_t)c * CL_ * D_ + d;
    for (int ll = 0; ll < CL_; ++ll) {
        float v  = h2f(V[base + (size_t)ll * D_]);
        float kp = h2f(KP[base + (size_t)ll * D_]);
        float pp = PP[pbase + (size_t)ll * D_];
        float sk, ck, sp, cp;
        sincosf(kp, &sk, &ck);
        sincosf(pp, &sp, &cp);
        cr += v * ck; ci += v * sk;
        pr += v * cp; pi += v * sp;
    }
    const size_t sidx = ((size_t)b * NC_ + c) * D_ + d;
    Scr[sidx] = cr; Sci[sidx] = ci; Spr[sidx] = pr; Spi[sidx] = pi;
}

// ---------------------------------------------------------------------------
// Pass B: in-place exclusive scan over chunks, per (b,d)
// ---------------------------------------------------------------------------
__global__ __launch_bounds__(256)
void passB(float* __restrict__ Scr, float* __restrict__ Sci,
           float* __restrict__ Spr, float* __restrict__ Spi)
{
    const int idx = blockIdx.x * 256 + threadIdx.x;  // 0..B*D-1
    const int b = idx >> 10;
    const int d = idx & 1023;
    float rcr = 0.f, rci = 0.f, rpr = 0.f, rpi = 0.f;
    for (int c = 0; c < NC_; ++c) {
        const size_t s = ((size_t)b * NC_ + c) * D_ + d;
        float t;
        t = Scr[s]; Scr[s] = rcr; rcr += t;
        t = Sci[s]; Sci[s] = rci; rci += t;
        t = Spr[s]; Spr[s] = rpr; rpr += t;
        t = Spi[s]; Spi[s] = rpi; rpi += t;
    }
}

// ---------------------------------------------------------------------------
// Pass C: replay scan, combine with gate, /sqrt(pos), fused LayerNorm over D.
// Writes Y as bf16 (Yb aliases KP's buffer: each element read-then-written
// exactly once by its owning thread; both are short* so no aliasing UB).
// ---------------------------------------------------------------------------
__global__ __launch_bounds__(1024)
void passC(const short* __restrict__ V, const short* KP,
           const short* __restrict__ QP, const float* __restrict__ PP,
           const float* __restrict__ gate, const float* __restrict__ Scr,
           const float* __restrict__ Sci, const float* __restrict__ Spr,
           const float* __restrict__ Spi, const float* __restrict__ ln_g,
           const float* __restrict__ ln_b, short* Yb)
{
    const int bid = blockIdx.x;
    const int b = bid >> 6;     // / NC_
    const int c = bid & 63;
    const int d = threadIdx.x;

    const size_t sidx = ((size_t)b * NC_ + c) * D_ + d;
    float cr = Scr[sidx], ci = Sci[sidx], pr = Spr[sidx], pi = Spi[sidx];
    const float g_ln = ln_g[d];
    const float b_ln = ln_b[d];

    __shared__ float2 lred[16];
    const int wid = threadIdx.x >> 6;
    const int lane = threadIdx.x & 63;

    for (int l0 = 0; l0 < CL_; ++l0) {
        const int ll = c * CL_ + l0;
        const size_t off = ((size_t)b * L_ + ll) * D_ + d;
        float v  = h2f(V[off]);
        float kp = h2f(KP[off]);
        float qp = h2f(QP[off]);
        float pp = PP[(size_t)ll * D_ + d];
        float gv = gate[b * L_ + ll];

        float sk, ck, sq, cq, sp, cp;
        sincosf(kp, &sk, &ck);
        sincosf(qp, &sq, &cq);
        sincosf(pp, &sp, &cp);

        cr += v * ck; ci += v * sk;
        pr += v * cp; pi += v * sp;

        float content = cr * cq + ci * sq;
        float posr    = pr * cp + pi * sp;
        float comb    = gv * content + (1.0f - gv) * posr;
        float u       = comb * rsqrtf((float)(ll + 1));

        float s = u, s2 = u * u;
        #pragma unroll
        for (int o = 32; o; o >>= 1) {
            s  += __shfl_down(s, o);
            s2 += __shfl_down(s2, o);
        }
        if (lane == 0) lred[wid] = make_float2(s, s2);
        __syncthreads();
        float ts = 0.f, ts2 = 0.f;
        #pragma unroll
        for (int i = 0; i < 16; ++i) { ts += lred[i].x; ts2 += lred[i].y; }
        const float mu  = ts * (1.0f / D_);
        const float var = ts2 * (1.0f / D_) - mu * mu;
        const float y = (u - mu) * rsqrtf(var + LN_EPS_F) * g_ln + b_ln;
        Yb[off] = f2bf(y);
        __syncthreads();
    }
}

// ---------------------------------------------------------------------------
extern "C" void kernel_launch(void* const* d_in, const int* in_sizes, int n_in,
                              void* d_out, int out_size, void* d_ws, size_t ws_size,
                              hipStream_t stream)
{
    const float* x    = (const float*)d_in[0];
    const float* Wk   = (const float*)d_in[1];
    const float* bk   = (const float*)d_in[2];
    const float* Wq   = (const float*)d_in[3];
    const float* bq   = (const float*)d_in[4];
    const float* Wv   = (const float*)d_in[5];
    const float* bv   = (const float*)d_in[6];
    const float* ln_g = (const float*)d_in[7];
    const float* ln_b = (const float*)d_in[8];
    const float* Wo   = (const float*)d_in[9];
    const float* bo   = (const float*)d_in[10];
    const float* Wg1  = (const float*)d_in[11];
    const float* bg1  = (const float*)d_in[12];
    const float* Wg2  = (const float*)d_in[13];
    const float* bg2  = (const float*)d_in[14];
    const float* PP   = (const float*)d_in[15];

    float* out = (float*)d_out;

    const size_t BLD = (size_t)B_ * L_ * D_;            // 16,777,216
    const size_t SZ_X   = BLD * 2;                      // 33,554,432 B
    const size_t SZ_W   = (size_t)D_ * D_ * 2;          //  2,097,152 B
    const size_t SZ_WG1 = (size_t)D_ * DG_ * 2;         //    524,288 B
    const size_t NEED = SZ_X + 5 * SZ_W + SZ_WG1 + 3 * SZ_X;  // 145,227,776
    if (ws_size < NEED) {
        hipMemcpyAsync(d_out, d_in[0], BLD * sizeof(float),
                       hipMemcpyDeviceToDevice, stream);
        return;
    }

    char* wsb = (char*)d_ws;
    short* xh   = (short*)(wsb);                          // [M][1024] bf16
    char*  wt   = wsb + SZ_X;
    short* WtKh = (short*)(wt);
    short* WtKl = (short*)(wt + 1 * SZ_W);
    short* WtQh = (short*)(wt + 2 * SZ_W);
    short* WtQl = (short*)(wt + 3 * SZ_W);
    short* WtV  = (short*)(wt + 4 * SZ_W);
    short* WtG1 = (short*)(wt + 5 * SZ_W);
    short* KP   = (short*)(wt + 5 * SZ_W + SZ_WG1);       // fp16 pattern
    short* QP   = (short*)((char*)KP + SZ_X);
    short* V    = (short*)((char*)QP + SZ_X);
    // aliases into dead regions:
    short* H    = WtKh;                                   // 8.39MB <= 10.49MB (WtKh..WtV), after those GEMMs
    float* Scr  = (float*)(wsb);                          // xh dead after H GEMM
    float* Sci  = (float*)(wsb + 1 * 1048576);
    float* Spr  = (float*)(wsb + 2 * 1048576);
    float* Spi  = (float*)(wsb + 3 * 1048576);
    float* gate = (float*)(wsb + 4 * 1048576);
    short* WtO  = (short*)(wsb + 4 * 1048576 + 65536);
    short* Yb   = KP;                                     // bf16 into KP slots (passC)

    const int M = B_ * L_;
    dim3 blk(256);

    // 1. conversions (WtO deferred: its space is inside live xh)
    conv_x<<<(int)(BLD / 8 / 256), blk, 0, stream>>>(x, xh, (int)(BLD / 8));
    convT<true ><<<D_ * D_ / 256, blk, 0, stream>>>(Wk, WtKh, WtKl, D_);
    convT<true ><<<D_ * D_ / 256, blk, 0, stream>>>(Wq, WtQh, WtQl, D_);
    convT<false><<<D_ * D_ / 256, blk, 0, stream>>>(Wv, WtV, nullptr, D_);
    convT<false><<<D_ * DG_ / 256, blk, 0, stream>>>(Wg1, WtG1, nullptr, DG_);

    // 2. input GEMMs
    dim3 gD(D_ / 128, M / 128);
    dim3 gG(DG_ / 128, M / 128);
    mgemm<1, true,  short><<<gD, blk, 0, stream>>>(xh, WtKh, WtKl, bk, nullptr, KP, M, D_, D_);
    mgemm<1, true,  short><<<gD, blk, 0, stream>>>(xh, WtQh, WtQl, bq, nullptr, QP, M, D_, D_);
    mgemm<0, false, short><<<gD, blk, 0, stream>>>(xh, WtV,  nullptr, bv, nullptr, V, M, D_, D_);
    mgemm<2, false, short><<<gG, blk, 0, stream>>>(xh, WtG1, nullptr, bg1, nullptr, H, M, DG_, D_);

    // 3. gate + deferred Wo conversion (xh dead now)
    gate_kernel<<<M / 4, blk, 0, stream>>>(H, Wg2, bg2, gate);
    convT<false><<<D_ * D_ / 256, blk, 0, stream>>>(Wo, WtO, nullptr, D_);

    // 4. scans + fused LN
    passA<<<B_ * NC_ * 4, blk, 0, stream>>>(V, KP, PP, Scr, Sci, Spr, Spi);
    passB<<<(B_ * D_) / 256, blk, 0, stream>>>(Scr, Sci, Spr, Spi);
    passC<<<B_ * NC_, 1024, 0, stream>>>(V, KP, QP, PP, gate, Scr, Sci, Spr, Spi,
                                         ln_g, ln_b, Yb);

    // 5. output GEMM (+ residual)
    mgemm<3, false, float><<<gD, blk, 0, stream>>>(Yb, WtO, nullptr, bo, x, out, M, D_, D_);
}

// Round 4
// 544.282 us; speedup vs baseline: 3.9297x; 1.0910x over previous
//
#include <hip/hip_runtime.h>
#include <math.h>

#define B_ 4
#define L_ 4096
#define D_ 1024
#define DG_ 256
#define NC_ 64          // number of chunks along L
#define CL_ 64          // chunk length (L_/NC_)
#define PI_F 3.14159265358979323846f
#define LN_EPS_F 1e-5f

typedef __attribute__((ext_vector_type(8))) _Float16 f16x8;
typedef __attribute__((ext_vector_type(8))) short s16x8;
typedef __attribute__((ext_vector_type(4))) short s16x4;
typedef __attribute__((ext_vector_type(4))) float f32x4;

__device__ inline short f2h(float f) { return __builtin_bit_cast(short, (_Float16)f); }
__device__ inline float h2f(short s) { return (float)__builtin_bit_cast(_Float16, s); }

__device__ inline void gld16(const void* g, void* l) {
    __builtin_amdgcn_global_load_lds(
        (const __attribute__((address_space(1))) unsigned int*)g,
        (__attribute__((address_space(3))) unsigned int*)l, 16, 0, 0);
}

// ---------------------------------------------------------------------------
// conv_x: fp32 -> fp16, 8 elems/thread
// ---------------------------------------------------------------------------
__global__ __launch_bounds__(256)
void conv_x(const float* __restrict__ x, short* __restrict__ xh, int n8)
{
    int t = blockIdx.x * 256 + threadIdx.x;
    if (t >= n8) return;
    const float4* p = (const float4*)x + (size_t)t * 2;
    float4 a = p[0], b = p[1];
    s16x8 v;
    v[0] = f2h(a.x); v[1] = f2h(a.y); v[2] = f2h(a.z); v[3] = f2h(a.w);
    v[4] = f2h(b.x); v[5] = f2h(b.y); v[6] = f2h(b.z); v[7] = f2h(b.w);
    *(s16x8*)(xh + (size_t)t * 8) = v;
}

// ---------------------------------------------------------------------------
// convT: W[1024][N] fp32 -> Th[N][1024] fp16   (transposed weights)
// ---------------------------------------------------------------------------
__global__ __launch_bounds__(256)
void convT(const float* __restrict__ W, short* __restrict__ Th, int N)
{
    int idx = blockIdx.x * 256 + threadIdx.x;   // over N*1024
    int n = idx >> 10, k = idx & 1023;
    Th[idx] = f2h(W[(size_t)k * N + n]);
}

// ---------------------------------------------------------------------------
// MFMA fp16 GEMM, m97 structure: 128x128 tile, BK=32, 4 waves (2x2), 4x4 frags.
//   out = epi( A[M,K] @ Bt[N,K]^T + bias )
// Grid: (x = M/128, y = N/128) -> linear id mod 8 == bm-block mod 8 ==> all
// blocks sharing an A-panel land on the same XCD (A L2-resident).
// EPI: 2 = gelu -> fp16 out0
//      3 = +X residual -> fp32 out0
//      4 = fused QKV: col<1024 tanh*pi->out0, <2048 tanh*pi->out1, else ->out2
// ---------------------------------------------------------------------------
template<int EPI, typename OT>
__global__ __launch_bounds__(256)
void mgemm(const short* __restrict__ A, const short* __restrict__ Bt,
           const float* __restrict__ X, OT* __restrict__ out0,
           short* __restrict__ out1, short* __restrict__ out2,
           const float* __restrict__ b0, const float* __restrict__ b1,
           const float* __restrict__ b2, int M, int N, int K)
{
    __shared__ __align__(16) short As[128 * 32];
    __shared__ __align__(16) short Bs[128 * 32];

    const int tid = threadIdx.x;
    const int w  = tid >> 6, l = tid & 63;
    const int wr = w >> 1,  wc = w & 1;
    const int fr = l & 15,  kb = l >> 4;
    const int bm = blockIdx.x * 128, bn = blockIdx.y * 128;   // swapped dims

    const int srow = l >> 2;             // row within 16-row chunk
    const int scol = (l & 3) * 8;        // fp16 elems (16B per lane)
    const short* gA0 = A  + (size_t)(bm + w * 32 +  0 + srow) * K + scol;
    const short* gA1 = A  + (size_t)(bm + w * 32 + 16 + srow) * K + scol;
    const short* gB0 = Bt + (size_t)(bn + w * 32 +  0 + srow) * K + scol;
    const short* gB1 = Bt + (size_t)(bn + w * 32 + 16 + srow) * K + scol;
    short* lA0 = &As[(w * 32 +  0) * 32];
    short* lA1 = &As[(w * 32 + 16) * 32];
    short* lB0 = &Bs[(w * 32 +  0) * 32];
    short* lB1 = &Bs[(w * 32 + 16) * 32];

    f32x4 acc[4][4] = {};

    for (int k0 = 0; k0 < K; k0 += 32) {
        gld16(gA0 + k0, lA0); gld16(gA1 + k0, lA1);
        gld16(gB0 + k0, lB0); gld16(gB1 + k0, lB1);
        __syncthreads();

        f16x8 af[4], bfr[4];
        #pragma unroll
        for (int m = 0; m < 4; ++m)
            af[m] = *(const f16x8*)&As[(wr * 64 + m * 16 + fr) * 32 + kb * 8];
        #pragma unroll
        for (int n = 0; n < 4; ++n)
            bfr[n] = *(const f16x8*)&Bs[(wc * 64 + n * 16 + fr) * 32 + kb * 8];
        #pragma unroll
        for (int m = 0; m < 4; ++m)
            #pragma unroll
            for (int n = 0; n < 4; ++n)
                acc[m][n] = __builtin_amdgcn_mfma_f32_16x16x32_f16(af[m], bfr[n], acc[m][n], 0, 0, 0);
        __syncthreads();
    }

    // epilogue: C/D layout col=lane&15, row=(lane>>4)*4+reg  [guide m89/m91]
    #pragma unroll
    for (int n = 0; n < 4; ++n) {
        const int col = bn + wc * 64 + n * 16 + fr;
        if constexpr (EPI == 4) {
            short* op; const float* bp; int cc; bool dt;
            if (col < 1024)      { op = (short*)out0; bp = b0; cc = col;        dt = true;  }
            else if (col < 2048) { op = out1;         bp = b1; cc = col - 1024; dt = true;  }
            else                 { op = out2;         bp = b2; cc = col - 2048; dt = false; }
            const float bcol = bp[cc];
            #pragma unroll
            for (int m = 0; m < 4; ++m)
                #pragma unroll
                for (int r = 0; r < 4; ++r) {
                    const int row = bm + wr * 64 + m * 16 + kb * 4 + r;
                    float c = acc[m][n][r] + bcol;
                    if (dt) c = tanhf(c) * PI_F;
                    op[(size_t)row * 1024 + cc] = f2h(c);
                }
        } else {
            const float bcol = b0[col];
            #pragma unroll
            for (int m = 0; m < 4; ++m)
                #pragma unroll
                for (int r = 0; r < 4; ++r) {
                    const int row = bm + wr * 64 + m * 16 + kb * 4 + r;
                    float c = acc[m][n][r] + bcol;
                    if constexpr (EPI == 2) {
                        float t = 0.7978845608028654f * (c + 0.044715f * c * c * c);
                        c = 0.5f * c * (1.0f + tanhf(t));
                        ((short*)out0)[(size_t)row * N + col] = f2h(c);
                    } else {   // EPI == 3
                        c += X[(size_t)row * N + col];
                        ((float*)out0)[(size_t)row * N + col] = c;
                    }
                }
        }
    }
}

// ---------------------------------------------------------------------------
// gate[row] = sigmoid( H[row,:] . Wg2 + bg2 )
// ---------------------------------------------------------------------------
__global__ __launch_bounds__(256)
void gate_kernel(const short* __restrict__ H, const float* __restrict__ Wg2,
                 const float* __restrict__ bg2, float* __restrict__ gate)
{
    const int wid = threadIdx.x >> 6;
    const int lane = threadIdx.x & 63;
    const int row = blockIdx.x * 4 + wid;
    s16x4 hv = *(const s16x4*)&H[(size_t)row * DG_ + lane * 4];
    float4 wv = *(const float4*)&Wg2[lane * 4];
    float s = h2f(hv[0]) * wv.x + h2f(hv[1]) * wv.y + h2f(hv[2]) * wv.z + h2f(hv[3]) * wv.w;
    #pragma unroll
    for (int o = 32; o; o >>= 1) s += __shfl_down(s, o);
    if (lane == 0) gate[row] = 1.0f / (1.0f + expf(-(s + bg2[0])));
}

// ---------------------------------------------------------------------------
// Pass A: per-chunk sums of V*cos(kp), V*sin(kp), V*cos(pp), V*sin(pp)
// 4 d/thread, grid = B*NC blocks x 256 threads
// ---------------------------------------------------------------------------
__global__ __launch_bounds__(256)
void passA(const short* __restrict__ V, const short* __restrict__ KP,
           const float* __restrict__ PP, float* __restrict__ Scr,
           float* __restrict__ Sci, float* __restrict__ Spr,
           float* __restrict__ Spi)
{
    const int bid = blockIdx.x;          // b*NC + c
    const int b = bid >> 6, c = bid & 63;
    const int d0 = threadIdx.x * 4;

    f32x4 cr = {}, ci = {}, pr = {}, pi = {};
    const size_t base  = ((size_t)b * L_ + (size_t)c * CL_) * D_ + d0;
    const size_t pbase = (size_t)c * CL_ * D_ + d0;
    for (int ll = 0; ll < CL_; ++ll) {
        s16x4 v4  = *(const s16x4*)&V [base + (size_t)ll * D_];
        s16x4 kp4 = *(const s16x4*)&KP[base + (size_t)ll * D_];
        f32x4 pp4 = *(const f32x4*)&PP[pbase + (size_t)ll * D_];
        #pragma unroll
        for (int j = 0; j < 4; ++j) {
            float v = h2f(v4[j]);
            float sk, ck, sp, cp;
            sincosf(h2f(kp4[j]), &sk, &ck);
            sincosf(pp4[j], &sp, &cp);
            cr[j] += v * ck; ci[j] += v * sk;
            pr[j] += v * cp; pi[j] += v * sp;
        }
    }
    const size_t sidx = ((size_t)b * NC_ + c) * D_ + d0;
    *(f32x4*)&Scr[sidx] = cr; *(f32x4*)&Sci[sidx] = ci;
    *(f32x4*)&Spr[sidx] = pr; *(f32x4*)&Spi[sidx] = pi;
}

// ---------------------------------------------------------------------------
// Pass B: in-place exclusive scan over chunks, per (b, 4 d's)
// ---------------------------------------------------------------------------
__global__ __launch_bounds__(256)
void passB(float* __restrict__ Scr, float* __restrict__ Sci,
           float* __restrict__ Spr, float* __restrict__ Spi)
{
    const int t = blockIdx.x * 256 + threadIdx.x;   // 0..B*D/4-1
    const int b = t >> 8;
    const int d0 = (t & 255) * 4;
    f32x4 rcr = {}, rci = {}, rpr = {}, rpi = {};
    for (int c = 0; c < NC_; ++c) {
        const size_t s = ((size_t)b * NC_ + c) * D_ + d0;
        f32x4 t4;
        t4 = *(f32x4*)&Scr[s]; *(f32x4*)&Scr[s] = rcr; rcr += t4;
        t4 = *(f32x4*)&Sci[s]; *(f32x4*)&Sci[s] = rci; rci += t4;
        t4 = *(f32x4*)&Spr[s]; *(f32x4*)&Spr[s] = rpr; rpr += t4;
        t4 = *(f32x4*)&Spi[s]; *(f32x4*)&Spi[s] = rpi; rpi += t4;
    }
}

// ---------------------------------------------------------------------------
// Pass C: replay scan, combine with gate, /sqrt(pos), fused LayerNorm over D.
// 256 threads, 4 d/thread. Yb aliases KP (each slot read-then-written by its
// owning thread within one iteration).
// ---------------------------------------------------------------------------
__global__ __launch_bounds__(256)
void passC(const short* __restrict__ V, const short* KP,
           const short* __restrict__ QP, const float* __restrict__ PP,
           const float* __restrict__ gate, const float* __restrict__ Scr,
           const float* __restrict__ Sci, const float* __restrict__ Spr,
           const float* __restrict__ Spi, const float* __restrict__ ln_g,
           const float* __restrict__ ln_b, short* Yb)
{
    const int bid = blockIdx.x;
    const int b = bid >> 6, c = bid & 63;
    const int d0 = threadIdx.x * 4;

    const size_t sidx = ((size_t)b * NC_ + c) * D_ + d0;
    f32x4 cr = *(const f32x4*)&Scr[sidx];
    f32x4 ci = *(const f32x4*)&Sci[sidx];
    f32x4 pr = *(const f32x4*)&Spr[sidx];
    f32x4 pi = *(const f32x4*)&Spi[sidx];
    const f32x4 g_ln = *(const f32x4*)&ln_g[d0];
    const f32x4 b_ln = *(const f32x4*)&ln_b[d0];

    __shared__ float2 lred[4];
    const int wid = threadIdx.x >> 6;
    const int lane = threadIdx.x & 63;

    for (int l0 = 0; l0 < CL_; ++l0) {
        const int ll = c * CL_ + l0;
        const size_t off = ((size_t)b * L_ + ll) * D_ + d0;
        s16x4 v4  = *(const s16x4*)&V [off];
        s16x4 kp4 = *(const s16x4*)&KP[off];
        s16x4 qp4 = *(const s16x4*)&QP[off];
        f32x4 pp4 = *(const f32x4*)&PP[(size_t)ll * D_ + d0];
        const float gv = gate[b * L_ + ll];
        const float rs_pos = rsqrtf((float)(ll + 1));

        f32x4 u;
        #pragma unroll
        for (int j = 0; j < 4; ++j) {
            float v = h2f(v4[j]);
            float sk, ck, sq, cq, sp, cp;
            sincosf(h2f(kp4[j]), &sk, &ck);
            sincosf(h2f(qp4[j]), &sq, &cq);
            sincosf(pp4[j], &sp, &cp);
            cr[j] += v * ck; ci[j] += v * sk;
            pr[j] += v * cp; pi[j] += v * sp;
            float content = cr[j] * cq + ci[j] * sq;
            float posr    = pr[j] * cp + pi[j] * sp;
            u[j] = (gv * content + (1.0f - gv) * posr) * rs_pos;
        }

        float s  = u[0] + u[1] + u[2] + u[3];
        float s2 = u[0]*u[0] + u[1]*u[1] + u[2]*u[2] + u[3]*u[3];
        #pragma unroll
        for (int o = 32; o; o >>= 1) {
            s  += __shfl_down(s, o);
            s2 += __shfl_down(s2, o);
        }
        if (lane == 0) lred[wid] = make_float2(s, s2);
        __syncthreads();
        float ts  = lred[0].x + lred[1].x + lred[2].x + lred[3].x;
        float ts2 = lred[0].y + lred[1].y + lred[2].y + lred[3].y;
        const float mu  = ts * (1.0f / D_);
        const float var = ts2 * (1.0f / D_) - mu * mu;
        const float rsv = rsqrtf(var + LN_EPS_F);
        s16x4 yo;
        #pragma unroll
        for (int j = 0; j < 4; ++j)
            yo[j] = f2h((u[j] - mu) * rsv * g_ln[j] + b_ln[j]);
        *(s16x4*)&Yb[off] = yo;
        __syncthreads();
    }
}

// ---------------------------------------------------------------------------
extern "C" void kernel_launch(void* const* d_in, const int* in_sizes, int n_in,
                              void* d_out, int out_size, void* d_ws, size_t ws_size,
                              hipStream_t stream)
{
    const float* x    = (const float*)d_in[0];
    const float* Wk   = (const float*)d_in[1];
    const float* bk   = (const float*)d_in[2];
    const float* Wq   = (const float*)d_in[3];
    const float* bq   = (const float*)d_in[4];
    const float* Wv   = (const float*)d_in[5];
    const float* bv   = (const float*)d_in[6];
    const float* ln_g = (const float*)d_in[7];
    const float* ln_b = (const float*)d_in[8];
    const float* Wo   = (const float*)d_in[9];
    const float* bo   = (const float*)d_in[10];
    const float* Wg1  = (const float*)d_in[11];
    const float* bg1  = (const float*)d_in[12];
    const float* Wg2  = (const float*)d_in[13];
    const float* bg2  = (const float*)d_in[14];
    const float* PP   = (const float*)d_in[15];

    float* out = (float*)d_out;

    const size_t BLD   = (size_t)B_ * L_ * D_;           // 16,777,216
    const size_t SZ_X  = BLD * 2;                        // 33,554,432
    const size_t SZ_R1 = (size_t)B_ * L_ * DG_ * 2;      //  8,388,608 (>= Wcat 6.29MB)
    const size_t SZ_G1 = (size_t)D_ * DG_ * 2;           //    524,288
    const size_t NEED  = SZ_X + SZ_R1 + SZ_G1 + 3 * SZ_X;  // 143,130,624
    if (ws_size < NEED) {
        hipMemcpyAsync(d_out, d_in[0], BLD * sizeof(float),
                       hipMemcpyDeviceToDevice, stream);
        return;
    }

    char* wsb = (char*)d_ws;
    short* xh   = (short*)(wsb);                          // region0: fp16 x
    char*  r1   = wsb + SZ_X;                             // region1: Wcat then H
    short* Wcat = (short*)r1;                             // [3072][1024] fp16
    short* H    = (short*)r1;                             // [16384][256] fp16 (after QKV GEMM)
    short* Wg1T = (short*)(r1 + SZ_R1);                   // [256][1024] fp16
    short* KP   = (short*)(r1 + SZ_R1 + SZ_G1);
    short* QP   = (short*)((char*)KP + SZ_X);
    short* V    = (short*)((char*)QP + SZ_X);
    // aliases into region0 (xh dead after H GEMM):
    float* gate = (float*)(wsb);
    float* Scr  = (float*)(wsb + 65536);
    float* Sci  = (float*)(wsb + 65536 + 1 * 1048576);
    float* Spr  = (float*)(wsb + 65536 + 2 * 1048576);
    float* Spi  = (float*)(wsb + 65536 + 3 * 1048576);
    short* WtO  = (short*)(wsb + 65536 + 4 * 1048576);    // [1024][1024] fp16
    short* Yb   = KP;                                     // passC writes over KP

    const int M = B_ * L_;
    dim3 blk(256);

    // 1. conversions (x and QKV weights; Wo deferred — its space is live xh)
    conv_x<<<(int)(BLD / 8 / 256), blk, 0, stream>>>(x, xh, (int)(BLD / 8));
    convT<<<D_ * D_ / 256, blk, 0, stream>>>(Wk, Wcat + 0 * D_ * D_, D_);
    convT<<<D_ * D_ / 256, blk, 0, stream>>>(Wq, Wcat + 1 * D_ * D_, D_);
    convT<<<D_ * D_ / 256, blk, 0, stream>>>(Wv, Wcat + 2 * D_ * D_, D_);
    convT<<<D_ * DG_ / 256, blk, 0, stream>>>(Wg1, Wg1T, DG_);

    // 2. fused QKV GEMM (N=3072), then H GEMM (H overwrites dead Wcat)
    dim3 gQKV(M / 128, 3072 / 128);
    dim3 gH(M / 128, DG_ / 128);
    dim3 gD(M / 128, D_ / 128);
    mgemm<4, short><<<gQKV, blk, 0, stream>>>(xh, Wcat, nullptr, KP, QP, V,
                                              bk, bq, bv, M, 3072, D_);
    mgemm<2, short><<<gH, blk, 0, stream>>>(xh, Wg1T, nullptr, H, nullptr, nullptr,
                                            bg1, nullptr, nullptr, M, DG_, D_);

    // 3. gate + deferred Wo conversion (xh dead now)
    gate_kernel<<<M / 4, blk, 0, stream>>>(H, Wg2, bg2, gate);
    convT<<<D_ * D_ / 256, blk, 0, stream>>>(Wo, WtO, D_);

    // 4. scans + fused LN
    passA<<<B_ * NC_, blk, 0, stream>>>(V, KP, PP, Scr, Sci, Spr, Spi);
    passB<<<(B_ * D_ / 4) / 256, blk, 0, stream>>>(Scr, Sci, Spr, Spi);
    passC<<<B_ * NC_, blk, 0, stream>>>(V, KP, QP, PP, gate, Scr, Sci, Spr, Spi,
                                        ln_g, ln_b, Yb);

    // 5. output GEMM (+ residual)
    mgemm<3, float><<<gD, blk, 0, stream>>>(Yb, WtO, x, out, nullptr, nullptr,
                                            bo, nullptr, nullptr, M, D_, D_);
}

// Round 5
// 376.215 us; speedup vs baseline: 5.6852x; 1.4467x over previous
//
#include <hip/hip_runtime.h>
#include <math.h>

#define B_ 4
#define L_ 4096
#define D_ 1024
#define DG_ 256
#define NC_ 128         // number of chunks along L
#define CL_ 32          // chunk length (L_/NC_)
#define PI_F 3.14159265358979323846f
#define LN_EPS_F 1e-5f

typedef __attribute__((ext_vector_type(8))) _Float16 f16x8;
typedef __attribute__((ext_vector_type(8))) short s16x8;
typedef __attribute__((ext_vector_type(4))) short s16x4;
typedef __attribute__((ext_vector_type(4))) float f32x4;

__device__ inline short f2h(float f) { return __builtin_bit_cast(short, (_Float16)f); }
__device__ inline float h2f(short s) { return (float)__builtin_bit_cast(_Float16, s); }

// fast transcendentals on HW pipes (v_exp_f32 / v_sin_f32 / v_cos_f32)
__device__ inline float ftanh(float x) {
    float e = __expf(2.0f * x);
    return 1.0f - 2.0f / (e + 1.0f);
}
__device__ inline void fsincos(float x, float* s, float* c) {
    *s = __sinf(x); *c = __cosf(x);
}

__device__ inline void gld16(const void* g, void* l) {
    __builtin_amdgcn_global_load_lds(
        (const __attribute__((address_space(1))) unsigned int*)g,
        (__attribute__((address_space(3))) unsigned int*)l, 16, 0, 0);
}

// ---------------------------------------------------------------------------
// conv_x: fp32 -> fp16, 8 elems/thread
// ---------------------------------------------------------------------------
__global__ __launch_bounds__(256)
void conv_x(const float* __restrict__ x, short* __restrict__ xh, int n8)
{
    int t = blockIdx.x * 256 + threadIdx.x;
    if (t >= n8) return;
    const float4* p = (const float4*)x + (size_t)t * 2;
    float4 a = p[0], b = p[1];
    s16x8 v;
    v[0] = f2h(a.x); v[1] = f2h(a.y); v[2] = f2h(a.z); v[3] = f2h(a.w);
    v[4] = f2h(b.x); v[5] = f2h(b.y); v[6] = f2h(b.z); v[7] = f2h(b.w);
    *(s16x8*)(xh + (size_t)t * 8) = v;
}

// ---------------------------------------------------------------------------
// convT: W[1024][N] fp32 -> Th[N][1024] fp16, LDS-tiled transpose (coalesced
// both sides; 65-float row pitch -> 2-way-max bank aliasing, free)
// grid = (N/64, 16), block = 256
// ---------------------------------------------------------------------------
__global__ __launch_bounds__(256)
void convT(const float* __restrict__ W, short* __restrict__ Th, int N)
{
    __shared__ float tile[64][65];
    const int n0 = blockIdx.x * 64, k0 = blockIdx.y * 64;
    const int t = threadIdx.x;
    const int r = t >> 4, c4 = (t & 15) * 4;

    #pragma unroll
    for (int i = 0; i < 4; ++i) {
        float4 v = *(const float4*)&W[(size_t)(k0 + r + i * 16) * N + n0 + c4];
        tile[r + i * 16][c4 + 0] = v.x;
        tile[r + i * 16][c4 + 1] = v.y;
        tile[r + i * 16][c4 + 2] = v.z;
        tile[r + i * 16][c4 + 3] = v.w;
    }
    __syncthreads();
    #pragma unroll
    for (int i = 0; i < 4; ++i) {
        const int n = r + i * 16;
        s16x4 o;
        o[0] = f2h(tile[c4 + 0][n]);
        o[1] = f2h(tile[c4 + 1][n]);
        o[2] = f2h(tile[c4 + 2][n]);
        o[3] = f2h(tile[c4 + 3][n]);
        *(s16x4*)&Th[(size_t)(n0 + n) * 1024 + k0 + c4] = o;
    }
}

// ---------------------------------------------------------------------------
// MFMA fp16 GEMM, m97 structure: 128x128 tile, BK=32, 4 waves (2x2), 4x4 frags.
// EPI: 2 = gelu -> fp16; 3 = +X residual -> fp32;
//      4 = fused QKV: col<1024 tanh*pi->out0, <2048 ->out1, else plain ->out2
// ---------------------------------------------------------------------------
template<int EPI, typename OT>
__global__ __launch_bounds__(256)
void mgemm(const short* __restrict__ A, const short* __restrict__ Bt,
           const float* __restrict__ X, OT* __restrict__ out0,
           short* __restrict__ out1, short* __restrict__ out2,
           const float* __restrict__ b0, const float* __restrict__ b1,
           const float* __restrict__ b2, int M, int N, int K)
{
    __shared__ __align__(16) short As[128 * 32];
    __shared__ __align__(16) short Bs[128 * 32];

    const int tid = threadIdx.x;
    const int w  = tid >> 6, l = tid & 63;
    const int wr = w >> 1,  wc = w & 1;
    const int fr = l & 15,  kb = l >> 4;
    const int bm = blockIdx.x * 128, bn = blockIdx.y * 128;

    const int srow = l >> 2;
    const int scol = (l & 3) * 8;
    const short* gA0 = A  + (size_t)(bm + w * 32 +  0 + srow) * K + scol;
    const short* gA1 = A  + (size_t)(bm + w * 32 + 16 + srow) * K + scol;
    const short* gB0 = Bt + (size_t)(bn + w * 32 +  0 + srow) * K + scol;
    const short* gB1 = Bt + (size_t)(bn + w * 32 + 16 + srow) * K + scol;
    short* lA0 = &As[(w * 32 +  0) * 32];
    short* lA1 = &As[(w * 32 + 16) * 32];
    short* lB0 = &Bs[(w * 32 +  0) * 32];
    short* lB1 = &Bs[(w * 32 + 16) * 32];

    f32x4 acc[4][4] = {};

    for (int k0 = 0; k0 < K; k0 += 32) {
        gld16(gA0 + k0, lA0); gld16(gA1 + k0, lA1);
        gld16(gB0 + k0, lB0); gld16(gB1 + k0, lB1);
        __syncthreads();

        f16x8 af[4], bfr[4];
        #pragma unroll
        for (int m = 0; m < 4; ++m)
            af[m] = *(const f16x8*)&As[(wr * 64 + m * 16 + fr) * 32 + kb * 8];
        #pragma unroll
        for (int n = 0; n < 4; ++n)
            bfr[n] = *(const f16x8*)&Bs[(wc * 64 + n * 16 + fr) * 32 + kb * 8];
        #pragma unroll
        for (int m = 0; m < 4; ++m)
            #pragma unroll
            for (int n = 0; n < 4; ++n)
                acc[m][n] = __builtin_amdgcn_mfma_f32_16x16x32_f16(af[m], bfr[n], acc[m][n], 0, 0, 0);
        __syncthreads();
    }

    // epilogue: C/D layout col=lane&15, row=(lane>>4)*4+reg
    #pragma unroll
    for (int n = 0; n < 4; ++n) {
        const int col = bn + wc * 64 + n * 16 + fr;
        if constexpr (EPI == 4) {
            short* op; const float* bp; int cc; bool dt;
            if (col < 1024)      { op = (short*)out0; bp = b0; cc = col;        dt = true;  }
            else if (col < 2048) { op = out1;         bp = b1; cc = col - 1024; dt = true;  }
            else                 { op = out2;         bp = b2; cc = col - 2048; dt = false; }
            const float bcol = bp[cc];
            #pragma unroll
            for (int m = 0; m < 4; ++m)
                #pragma unroll
                for (int r = 0; r < 4; ++r) {
                    const int row = bm + wr * 64 + m * 16 + kb * 4 + r;
                    float c = acc[m][n][r] + bcol;
                    if (dt) c = ftanh(c) * PI_F;
                    op[(size_t)row * 1024 + cc] = f2h(c);
                }
        } else {
            const float bcol = b0[col];
            #pragma unroll
            for (int m = 0; m < 4; ++m)
                #pragma unroll
                for (int r = 0; r < 4; ++r) {
                    const int row = bm + wr * 64 + m * 16 + kb * 4 + r;
                    float c = acc[m][n][r] + bcol;
                    if constexpr (EPI == 2) {
                        float t = 0.7978845608028654f * (c + 0.044715f * c * c * c);
                        c = 0.5f * c * (1.0f + ftanh(t));
                        ((short*)out0)[(size_t)row * N + col] = f2h(c);
                    } else {   // EPI == 3
                        c += X[(size_t)row * N + col];
                        ((float*)out0)[(size_t)row * N + col] = c;
                    }
                }
        }
    }
}

// ---------------------------------------------------------------------------
// gate[row] = sigmoid( H[row,:] . Wg2 + bg2 )
// ---------------------------------------------------------------------------
__global__ __launch_bounds__(256)
void gate_kernel(const short* __restrict__ H, const float* __restrict__ Wg2,
                 const float* __restrict__ bg2, float* __restrict__ gate)
{
    const int wid = threadIdx.x >> 6;
    const int lane = threadIdx.x & 63;
    const int row = blockIdx.x * 4 + wid;
    s16x4 hv = *(const s16x4*)&H[(size_t)row * DG_ + lane * 4];
    float4 wv = *(const float4*)&Wg2[lane * 4];
    float s = h2f(hv[0]) * wv.x + h2f(hv[1]) * wv.y + h2f(hv[2]) * wv.z + h2f(hv[3]) * wv.w;
    #pragma unroll
    for (int o = 32; o; o >>= 1) s += __shfl_down(s, o);
    if (lane == 0) gate[row] = 1.0f / (1.0f + __expf(-(s + bg2[0])));
}

// ---------------------------------------------------------------------------
// Pass A: per-chunk sums of V*cos(kp), V*sin(kp), V*cos(pp), V*sin(pp)
// Interleaved state: SI[(b*NC+c)*D + d] = {cr, ci, pr, pi}
// grid = B*NC, block = 256, 4 d/thread
// ---------------------------------------------------------------------------
__global__ __launch_bounds__(256)
void passA(const short* __restrict__ V, const short* __restrict__ KP,
           const float* __restrict__ PP, f32x4* __restrict__ SI)
{
    const int bid = blockIdx.x;          // b*NC + c
    const int b = bid >> 7, c = bid & 127;
    const int d0 = threadIdx.x * 4;

    f32x4 cr = {}, ci = {}, pr = {}, pi = {};
    const size_t base  = ((size_t)b * L_ + (size_t)c * CL_) * D_ + d0;
    const size_t pbase = (size_t)c * CL_ * D_ + d0;
    for (int ll = 0; ll < CL_; ++ll) {
        s16x4 v4  = *(const s16x4*)&V [base + (size_t)ll * D_];
        s16x4 kp4 = *(const s16x4*)&KP[base + (size_t)ll * D_];
        f32x4 pp4 = *(const f32x4*)&PP[pbase + (size_t)ll * D_];
        #pragma unroll
        for (int j = 0; j < 4; ++j) {
            float v = h2f(v4[j]);
            float sk, ck, sp, cp;
            fsincos(h2f(kp4[j]), &sk, &ck);
            fsincos(pp4[j], &sp, &cp);
            cr[j] += v * ck; ci[j] += v * sk;
            pr[j] += v * cp; pi[j] += v * sp;
        }
    }
    const size_t sidx = ((size_t)bid << 10) + d0;
    #pragma unroll
    for (int j = 0; j < 4; ++j) {
        f32x4 o = { cr[j], ci[j], pr[j], pi[j] };
        SI[sidx + j] = o;
    }
}

// ---------------------------------------------------------------------------
// Pass B: in-place exclusive scan over chunks; one f32x4 per (b,c,d).
// grid = B*D/256 = 16, block = 256; perfectly coalesced 16B/lane.
// ---------------------------------------------------------------------------
__global__ __launch_bounds__(256)
void passB(f32x4* __restrict__ SI)
{
    const int t = blockIdx.x * 256 + threadIdx.x;   // 0..B*D-1
    const int b = t >> 10, d = t & 1023;
    f32x4 run = {};
    for (int c = 0; c < NC_; ++c) {
        const size_t idx = ((size_t)(b * NC_ + c) << 10) + d;
        f32x4 v = SI[idx];
        SI[idx] = run;
        run += v;
    }
}

// ---------------------------------------------------------------------------
// Pass C: replay scan, combine with gate, /sqrt(pos), fused LayerNorm over D.
// grid = B*NC, block = 256 (4 d/thread); 1 barrier/iter (double-buffered lred).
// Yb aliases KP (each slot read-then-written by its owning thread per iter).
// ---------------------------------------------------------------------------
__global__ __launch_bounds__(256)
void passC(const short* __restrict__ V, const short* KP,
           const short* __restrict__ QP, const float* __restrict__ PP,
           const float* __restrict__ gate, const f32x4* __restrict__ SI,
           const float* __restrict__ ln_g, const float* __restrict__ ln_b,
           short* Yb)
{
    const int bid = blockIdx.x;
    const int b = bid >> 7, c = bid & 127;
    const int d0 = threadIdx.x * 4;

    const size_t sidx = ((size_t)bid << 10) + d0;
    f32x4 cr, ci, pr, pi;
    #pragma unroll
    for (int j = 0; j < 4; ++j) {
        f32x4 s = SI[sidx + j];
        cr[j] = s[0]; ci[j] = s[1]; pr[j] = s[2]; pi[j] = s[3];
    }
    const f32x4 g_ln = *(const f32x4*)&ln_g[d0];
    const f32x4 b_ln = *(const f32x4*)&ln_b[d0];

    __shared__ float2 lred[2][4];
    const int wid = threadIdx.x >> 6;
    const int lane = threadIdx.x & 63;

    for (int l0 = 0; l0 < CL_; ++l0) {
        const int ll = c * CL_ + l0;
        const size_t off = ((size_t)b * L_ + ll) * D_ + d0;
        s16x4 v4  = *(const s16x4*)&V [off];
        s16x4 kp4 = *(const s16x4*)&KP[off];
        s16x4 qp4 = *(const s16x4*)&QP[off];
        f32x4 pp4 = *(const f32x4*)&PP[(size_t)ll * D_ + d0];
        const float gv = gate[b * L_ + ll];
        const float rs_pos = rsqrtf((float)(ll + 1));

        f32x4 u;
        #pragma unroll
        for (int j = 0; j < 4; ++j) {
            float v = h2f(v4[j]);
            float sk, ck, sq, cq, sp, cp;
            fsincos(h2f(kp4[j]), &sk, &ck);
            fsincos(h2f(qp4[j]), &sq, &cq);
            fsincos(pp4[j], &sp, &cp);
            cr[j] += v * ck; ci[j] += v * sk;
            pr[j] += v * cp; pi[j] += v * sp;
            float content = cr[j] * cq + ci[j] * sq;
            float posr    = pr[j] * cp + pi[j] * sp;
            u[j] = (gv * content + (1.0f - gv) * posr) * rs_pos;
        }

        float s  = u[0] + u[1] + u[2] + u[3];
        float s2 = u[0]*u[0] + u[1]*u[1] + u[2]*u[2] + u[3]*u[3];
        #pragma unroll
        for (int o = 32; o; o >>= 1) {
            s  += __shfl_down(s, o);
            s2 += __shfl_down(s2, o);
        }
        const int pb = l0 & 1;
        if (lane == 0) lred[pb][wid] = make_float2(s, s2);
        __syncthreads();
        float ts  = lred[pb][0].x + lred[pb][1].x + lred[pb][2].x + lred[pb][3].x;
        float ts2 = lred[pb][0].y + lred[pb][1].y + lred[pb][2].y + lred[pb][3].y;
        const float mu  = ts * (1.0f / D_);
        const float var = ts2 * (1.0f / D_) - mu * mu;
        const float rsv = rsqrtf(var + LN_EPS_F);
        s16x4 yo;
        #pragma unroll
        for (int j = 0; j < 4; ++j)
            yo[j] = f2h((u[j] - mu) * rsv * g_ln[j] + b_ln[j]);
        *(s16x4*)&Yb[off] = yo;
    }
}

// ---------------------------------------------------------------------------
extern "C" void kernel_launch(void* const* d_in, const int* in_sizes, int n_in,
                              void* d_out, int out_size, void* d_ws, size_t ws_size,
                              hipStream_t stream)
{
    const float* x    = (const float*)d_in[0];
    const float* Wk   = (const float*)d_in[1];
    const float* bk   = (const float*)d_in[2];
    const float* Wq   = (const float*)d_in[3];
    const float* bq   = (const float*)d_in[4];
    const float* Wv   = (const float*)d_in[5];
    const float* bv   = (const float*)d_in[6];
    const float* ln_g = (const float*)d_in[7];
    const float* ln_b = (const float*)d_in[8];
    const float* Wo   = (const float*)d_in[9];
    const float* bo   = (const float*)d_in[10];
    const float* Wg1  = (const float*)d_in[11];
    const float* bg1  = (const float*)d_in[12];
    const float* Wg2  = (const float*)d_in[13];
    const float* bg2  = (const float*)d_in[14];
    const float* PP   = (const float*)d_in[15];

    float* out = (float*)d_out;

    const size_t BLD   = (size_t)B_ * L_ * D_;           // 16,777,216
    const size_t SZ_X  = BLD * 2;                        // 33,554,432
    const size_t SZ_R1 = (size_t)B_ * L_ * DG_ * 2;      //  8,388,608 (>= Wcat 6.29MB)
    const size_t SZ_G1 = (size_t)D_ * DG_ * 2;           //    524,288
    const size_t NEED  = SZ_X + SZ_R1 + SZ_G1 + 3 * SZ_X;  // 143,130,624
    if (ws_size < NEED) {
        hipMemcpyAsync(d_out, d_in[0], BLD * sizeof(float),
                       hipMemcpyDeviceToDevice, stream);
        return;
    }

    char* wsb = (char*)d_ws;
    short* xh   = (short*)(wsb);                          // region0: fp16 x
    char*  r1   = wsb + SZ_X;                             // region1: Wcat then H
    short* Wcat = (short*)r1;                             // [3072][1024] fp16
    short* H    = (short*)r1;                             // [16384][256] fp16 (after QKV GEMM)
    short* Wg1T = (short*)(r1 + SZ_R1);                   // [256][1024] fp16
    short* KP   = (short*)(r1 + SZ_R1 + SZ_G1);
    short* QP   = (short*)((char*)KP + SZ_X);
    short* V    = (short*)((char*)QP + SZ_X);
    // aliases into region0 (xh dead after H GEMM):
    float* gate = (float*)(wsb);                          // 64 KB
    short* WtO  = (short*)(wsb + 65536);                  // 2 MB
    f32x4* SI   = (f32x4*)(wsb + 65536 + 2097152);        // 8 MB interleaved scans
    short* Yb   = KP;                                     // passC writes over KP

    const int M = B_ * L_;
    dim3 blk(256);

    // 1. conversions (x and QKV weights; Wo deferred — its space is live xh)
    conv_x<<<(int)(BLD / 8 / 256), blk, 0, stream>>>(x, xh, (int)(BLD / 8));
    dim3 gT(D_ / 64, 16);
    dim3 gTg(DG_ / 64, 16);
    convT<<<gT, blk, 0, stream>>>(Wk, Wcat + 0 * D_ * D_, D_);
    convT<<<gT, blk, 0, stream>>>(Wq, Wcat + 1 * D_ * D_, D_);
    convT<<<gT, blk, 0, stream>>>(Wv, Wcat + 2 * D_ * D_, D_);
    convT<<<gTg, blk, 0, stream>>>(Wg1, Wg1T, DG_);

    // 2. fused QKV GEMM (N=3072), then H GEMM (H overwrites dead Wcat)
    dim3 gQKV(M / 128, 3072 / 128);
    dim3 gH(M / 128, DG_ / 128);
    dim3 gD(M / 128, D_ / 128);
    mgemm<4, short><<<gQKV, blk, 0, stream>>>(xh, Wcat, nullptr, KP, QP, V,
                                              bk, bq, bv, M, 3072, D_);
    mgemm<2, short><<<gH, blk, 0, stream>>>(xh, Wg1T, nullptr, H, nullptr, nullptr,
                                            bg1, nullptr, nullptr, M, DG_, D_);

    // 3. gate + deferred Wo conversion (xh dead now)
    gate_kernel<<<M / 4, blk, 0, stream>>>(H, Wg2, bg2, gate);
    convT<<<gT, blk, 0, stream>>>(Wo, WtO, D_);

    // 4. scans + fused LN
    passA<<<B_ * NC_, blk, 0, stream>>>(V, KP, PP, SI);
    passB<<<(B_ * D_) / 256, blk, 0, stream>>>(SI);
    passC<<<B_ * NC_, blk, 0, stream>>>(V, KP, QP, PP, gate, SI, ln_g, ln_b, Yb);

    // 5. output GEMM (+ residual)
    mgemm<3, float><<<gD, blk, 0, stream>>>(Yb, WtO, x, out, nullptr, nullptr,
                                            bo, nullptr, nullptr, M, D_, D_);
}

// Round 6
// 328.390 us; speedup vs baseline: 6.5131x; 1.1456x over previous
//
#include <hip/hip_runtime.h>
#include <math.h>

#define B_ 4
#define L_ 4096
#define D_ 1024
#define DG_ 256
#define NC_ 128         // number of chunks along L
#define CL_ 32          // chunk length (L_/NC_)
#define PI_F 3.14159265358979323846f
#define LN_EPS_F 1e-5f

typedef __attribute__((ext_vector_type(8))) _Float16 f16x8;
typedef __attribute__((ext_vector_type(8))) short s16x8;
typedef __attribute__((ext_vector_type(4))) short s16x4;
typedef __attribute__((ext_vector_type(4))) float f32x4;

__device__ inline short f2h(float f) { return __builtin_bit_cast(short, (_Float16)f); }
__device__ inline float h2f(short s) { return (float)__builtin_bit_cast(_Float16, s); }

__device__ inline float ftanh(float x) {
    float e = __expf(2.0f * x);
    return 1.0f - 2.0f / (e + 1.0f);
}
__device__ inline void fsincos(float x, float* s, float* c) {
    *s = __sinf(x); *c = __cosf(x);
}

__device__ inline void gld16(const void* g, void* l) {
    __builtin_amdgcn_global_load_lds(
        (const __attribute__((address_space(1))) unsigned int*)g,
        (__attribute__((address_space(3))) unsigned int*)l, 16, 0, 0);
}

// ---------------------------------------------------------------------------
// conv_x: fp32 -> fp16, 8 elems/thread
// ---------------------------------------------------------------------------
__global__ __launch_bounds__(256)
void conv_x(const float* __restrict__ x, short* __restrict__ xh, int n8)
{
    int t = blockIdx.x * 256 + threadIdx.x;
    if (t >= n8) return;
    const float4* p = (const float4*)x + (size_t)t * 2;
    float4 a = p[0], b = p[1];
    s16x8 v;
    v[0] = f2h(a.x); v[1] = f2h(a.y); v[2] = f2h(a.z); v[3] = f2h(a.w);
    v[4] = f2h(b.x); v[5] = f2h(b.y); v[6] = f2h(b.z); v[7] = f2h(b.w);
    *(s16x8*)(xh + (size_t)t * 8) = v;
}

// ---------------------------------------------------------------------------
// convT: W[1024][N] fp32 -> Th[N][1024] fp16, LDS-tiled transpose
// ---------------------------------------------------------------------------
__global__ __launch_bounds__(256)
void convT(const float* __restrict__ W, short* __restrict__ Th, int N)
{
    __shared__ float tile[64][65];
    const int n0 = blockIdx.x * 64, k0 = blockIdx.y * 64;
    const int t = threadIdx.x;
    const int r = t >> 4, c4 = (t & 15) * 4;

    #pragma unroll
    for (int i = 0; i < 4; ++i) {
        float4 v = *(const float4*)&W[(size_t)(k0 + r + i * 16) * N + n0 + c4];
        tile[r + i * 16][c4 + 0] = v.x;
        tile[r + i * 16][c4 + 1] = v.y;
        tile[r + i * 16][c4 + 2] = v.z;
        tile[r + i * 16][c4 + 3] = v.w;
    }
    __syncthreads();
    #pragma unroll
    for (int i = 0; i < 4; ++i) {
        const int n = r + i * 16;
        s16x4 o;
        o[0] = f2h(tile[c4 + 0][n]);
        o[1] = f2h(tile[c4 + 1][n]);
        o[2] = f2h(tile[c4 + 2][n]);
        o[3] = f2h(tile[c4 + 3][n]);
        *(s16x4*)&Th[(size_t)(n0 + n) * 1024 + k0 + c4] = o;
    }
}

// ---------------------------------------------------------------------------
// 256x256 deep-pipelined MFMA fp16 GEMM. BK=64, 8 waves (2Mx4N), 512 thr.
// LDS 128KB double-buffered; row-XOR swizzle (read side + inverse on global
// source, since global_load_lds writes linearly); 4 MFMA-quadrant phases per
// K-tile; counted vmcnt(2) at tile boundaries (t+2's A-fronts in flight).
// EPI: 3 = +X residual -> fp32 out0
//      4 = fused QKV: bn<1024 tanh*pi->out0, <2048 tanh*pi->out1, else ->out2
// ---------------------------------------------------------------------------
__device__ inline f16x8 ldf(const char* lds, int ofs, int r, int colb) {
    return *(const f16x8*)(lds + ofs + r * 128 + (colb ^ ((r & 7) << 4)));
}

#define STG(srcp, rbase, kt, lofs)                                              \
    gld16((const char*)(srcp) + (size_t)((rbase) + sr) * (size_t)(K * 2) +      \
              (kt) * 128 + sc,                                                  \
          lds + (lofs) + (w << 10))

#define MFMA_Q(MG, NG)                                                          \
    _Pragma("unroll") for (int i_ = 0; i_ < 4; ++i_)                            \
    _Pragma("unroll") for (int j_ = 0; j_ < 2; ++j_)                            \
    _Pragma("unroll") for (int kk_ = 0; kk_ < 2; ++kk_)                         \
        acc[(MG)*4 + i_][(NG)*2 + j_] = __builtin_amdgcn_mfma_f32_16x16x32_f16( \
            af[i_][kk_], bq[NG][j_][kk_], acc[(MG)*4 + i_][(NG)*2 + j_], 0, 0, 0);

#define SBAR() __builtin_amdgcn_sched_barrier(0)

template<int EPI, typename OT>
__global__ __launch_bounds__(512, 2)
void mgemm256(const short* __restrict__ A, const short* __restrict__ Bt,
              const float* __restrict__ X, OT* __restrict__ out0,
              short* __restrict__ out1, short* __restrict__ out2,
              const float* __restrict__ b0, const float* __restrict__ b1,
              const float* __restrict__ b2, int M, int N, int K)
{
    extern __shared__ char lds[];   // 131072 bytes: 2 x (A 32KB + B 32KB)

    const int tid = threadIdx.x;
    const int w = tid >> 6, l = tid & 63;
    const int wr = w >> 2, wc = w & 3;          // 2 x 4 wave grid
    const int fr = l & 15, kb = l >> 4;
    const int bm = blockIdx.x * 256, bn = blockIdx.y * 256;
    const int nt = K >> 6;

    // staging lane geometry: 8KB region, thread t covers bytes [t*16, t*16+16)
    const int p0 = tid * 16;
    const int sr = p0 >> 7;                     // row 0..63 within region
    const int sc = (p0 & 127) ^ ((sr & 7) << 4);// inverse-swizzled source col

    f32x4 acc[8][4] = {};
    f16x8 af[4][2];        // A frags for current mg
    f16x8 bq[2][2][2];     // B frags [ng][nf-sub][kk], held across the tile

    // ---- prologue: stage tiles 0 and 1 completely -------------------------
    STG(A, bm +   0, 0, 0);             STG(A, bm + 128, 0, 16384);
    STG(A, bm +  64, 0, 8192);          STG(A, bm + 192, 0, 16384 + 8192);
    STG(Bt, bn +   0, 0, 32768);        STG(Bt, bn +  64, 0, 32768 + 8192);
    STG(Bt, bn + 128, 0, 32768 + 16384);STG(Bt, bn + 192, 0, 32768 + 16384 + 8192);
    STG(A, bm +   0, 1, 65536);         STG(A, bm + 128, 1, 65536 + 16384);
    STG(A, bm +  64, 1, 65536 + 8192);  STG(A, bm + 192, 1, 65536 + 16384 + 8192);
    STG(Bt, bn +   0, 1, 98304);        STG(Bt, bn +  64, 1, 98304 + 8192);
    STG(Bt, bn + 128, 1, 98304 + 16384);STG(Bt, bn + 192, 1, 98304 + 16384 + 8192);
    asm volatile("s_waitcnt vmcnt(8)" ::: "memory");   // tile 0 landed
    SBAR(); __builtin_amdgcn_s_barrier(); SBAR();

    for (int t = 0; t < nt; ++t) {
        const int Ab = (t & 1) << 16, Bb = Ab + 32768;
        const int An = ((t & 1) ^ 1) << 16, Bn = An + 32768;
        const bool sNext = (t >= 1) && (t + 1 < nt);   // t+1 parts (t=0 done in prologue)
        const bool sAF   = (t + 2 < nt);               // t+2 A-fronts into current buf

        // ---- P0: read A-mg0 + B-ng0; stage next A-backs
        #pragma unroll
        for (int i = 0; i < 4; ++i)
            #pragma unroll
            for (int kk = 0; kk < 2; ++kk)
                af[i][kk] = ldf(lds, Ab + (wr << 14), i * 16 + fr, (kk << 6) + (kb << 4));
        #pragma unroll
        for (int j = 0; j < 2; ++j)
            #pragma unroll
            for (int kk = 0; kk < 2; ++kk)
                bq[0][j][kk] = ldf(lds, Bb + ((wc >> 1) << 14),
                                   ((wc & 1) << 6) + j * 16 + fr, (kk << 6) + (kb << 4));
        if (sNext) { STG(A, bm + 64, t + 1, An + 8192); STG(A, bm + 192, t + 1, An + 16384 + 8192); }
        SBAR(); __builtin_amdgcn_s_barrier(); SBAR();
        __builtin_amdgcn_s_setprio(1);
        MFMA_Q(0, 0);
        __builtin_amdgcn_s_setprio(0);
        SBAR(); __builtin_amdgcn_s_barrier(); SBAR();

        // ---- P1: read B-ng1; stage next B-h0
        #pragma unroll
        for (int j = 0; j < 2; ++j)
            #pragma unroll
            for (int kk = 0; kk < 2; ++kk)
                bq[1][j][kk] = ldf(lds, Bb + ((wc >> 1) << 14),
                                   ((wc & 1) << 6) + (2 + j) * 16 + fr, (kk << 6) + (kb << 4));
        if (sNext) { STG(Bt, bn + 0, t + 1, Bn); STG(Bt, bn + 64, t + 1, Bn + 8192); }
        SBAR(); __builtin_amdgcn_s_barrier(); SBAR();
        __builtin_amdgcn_s_setprio(1);
        MFMA_Q(0, 1);
        __builtin_amdgcn_s_setprio(0);
        SBAR(); __builtin_amdgcn_s_barrier(); SBAR();

        // ---- P2: read A-mg1; stage next B-h1
        #pragma unroll
        for (int i = 0; i < 4; ++i)
            #pragma unroll
            for (int kk = 0; kk < 2; ++kk)
                af[i][kk] = ldf(lds, Ab + (wr << 14), (4 + i) * 16 + fr, (kk << 6) + (kb << 4));
        if (sNext) { STG(Bt, bn + 128, t + 1, Bn + 16384); STG(Bt, bn + 192, t + 1, Bn + 16384 + 8192); }
        SBAR(); __builtin_amdgcn_s_barrier(); SBAR();
        __builtin_amdgcn_s_setprio(1);
        MFMA_Q(1, 0);
        __builtin_amdgcn_s_setprio(0);
        SBAR(); __builtin_amdgcn_s_barrier(); SBAR();

        // ---- P3: stage t+2 A-fronts into CURRENT buf (region dead since P0)
        if (sAF) { STG(A, bm + 0, t + 2, Ab); STG(A, bm + 128, t + 2, Ab + 16384); }
        SBAR(); __builtin_amdgcn_s_barrier(); SBAR();
        __builtin_amdgcn_s_setprio(1);
        MFMA_Q(1, 1);
        __builtin_amdgcn_s_setprio(0);
        SBAR();
        if (t < nt - 1) {
            if (sAF) { asm volatile("s_waitcnt vmcnt(2)" ::: "memory"); }
            else     { asm volatile("s_waitcnt vmcnt(0)" ::: "memory"); }
            __builtin_amdgcn_s_barrier(); SBAR();
        }
    }

    // ---- epilogue: C/D layout col=lane&15, row=(lane>>4)*4+reg ------------
    if constexpr (EPI == 4) {
        short* op; const float* bp; bool dt;
        if (bn < 1024)      { op = (short*)out0; bp = b0; dt = true;  }
        else if (bn < 2048) { op = out1;         bp = b1; dt = true;  }
        else                { op = out2;         bp = b2; dt = false; }
        const int cb = bn & 1023;
        #pragma unroll
        for (int nf = 0; nf < 4; ++nf) {
            const int cc = cb + wc * 64 + nf * 16 + fr;
            const float bcol = bp[cc];
            #pragma unroll
            for (int mf = 0; mf < 8; ++mf)
                #pragma unroll
                for (int rr = 0; rr < 4; ++rr) {
                    const int row = bm + wr * 128 + mf * 16 + kb * 4 + rr;
                    float c = acc[mf][nf][rr] + bcol;
                    if (dt) c = ftanh(c) * PI_F;
                    op[(size_t)row * 1024 + cc] = f2h(c);
                }
        }
    } else {   // EPI == 3: +X residual -> fp32
        #pragma unroll
        for (int nf = 0; nf < 4; ++nf) {
            const int col = bn + wc * 64 + nf * 16 + fr;
            const float bcol = b0[col];
            #pragma unroll
            for (int mf = 0; mf < 8; ++mf)
                #pragma unroll
                for (int rr = 0; rr < 4; ++rr) {
                    const int row = bm + wr * 128 + mf * 16 + kb * 4 + rr;
                    float c = acc[mf][nf][rr] + bcol + X[(size_t)row * N + col];
                    ((float*)out0)[(size_t)row * N + col] = c;
                }
        }
    }
}

// ---------------------------------------------------------------------------
// 128x128 MFMA GEMM (m97 structure) — used for the small H GEMM (N=256).
// EPI: 2 = gelu -> fp16
// ---------------------------------------------------------------------------
template<int EPI>
__global__ __launch_bounds__(256)
void mgemm(const short* __restrict__ A, const short* __restrict__ Bt,
           short* __restrict__ out0, const float* __restrict__ b0,
           int M, int N, int K)
{
    __shared__ __align__(16) short As[128 * 32];
    __shared__ __align__(16) short Bs[128 * 32];

    const int tid = threadIdx.x;
    const int w  = tid >> 6, l = tid & 63;
    const int wr = w >> 1,  wc = w & 1;
    const int fr = l & 15,  kb = l >> 4;
    const int bm = blockIdx.x * 128, bn = blockIdx.y * 128;

    const int srow = l >> 2;
    const int scol = (l & 3) * 8;
    const short* gA0 = A  + (size_t)(bm + w * 32 +  0 + srow) * K + scol;
    const short* gA1 = A  + (size_t)(bm + w * 32 + 16 + srow) * K + scol;
    const short* gB0 = Bt + (size_t)(bn + w * 32 +  0 + srow) * K + scol;
    const short* gB1 = Bt + (size_t)(bn + w * 32 + 16 + srow) * K + scol;
    short* lA0 = &As[(w * 32 +  0) * 32];
    short* lA1 = &As[(w * 32 + 16) * 32];
    short* lB0 = &Bs[(w * 32 +  0) * 32];
    short* lB1 = &Bs[(w * 32 + 16) * 32];

    f32x4 acc[4][4] = {};

    for (int k0 = 0; k0 < K; k0 += 32) {
        gld16(gA0 + k0, lA0); gld16(gA1 + k0, lA1);
        gld16(gB0 + k0, lB0); gld16(gB1 + k0, lB1);
        __syncthreads();

        f16x8 afr[4], bfr[4];
        #pragma unroll
        for (int m = 0; m < 4; ++m)
            afr[m] = *(const f16x8*)&As[(wr * 64 + m * 16 + fr) * 32 + kb * 8];
        #pragma unroll
        for (int n = 0; n < 4; ++n)
            bfr[n] = *(const f16x8*)&Bs[(wc * 64 + n * 16 + fr) * 32 + kb * 8];
        #pragma unroll
        for (int m = 0; m < 4; ++m)
            #pragma unroll
            for (int n = 0; n < 4; ++n)
                acc[m][n] = __builtin_amdgcn_mfma_f32_16x16x32_f16(afr[m], bfr[n], acc[m][n], 0, 0, 0);
        __syncthreads();
    }

    #pragma unroll
    for (int n = 0; n < 4; ++n) {
        const int col = bn + wc * 64 + n * 16 + fr;
        const float bcol = b0[col];
        #pragma unroll
        for (int m = 0; m < 4; ++m)
            #pragma unroll
            for (int r = 0; r < 4; ++r) {
                const int row = bm + wr * 64 + m * 16 + kb * 4 + r;
                float c = acc[m][n][r] + bcol;
                float tt = 0.7978845608028654f * (c + 0.044715f * c * c * c);
                c = 0.5f * c * (1.0f + ftanh(tt));
                out0[(size_t)row * N + col] = f2h(c);
            }
    }
}

// ---------------------------------------------------------------------------
// gate[row] = sigmoid( H[row,:] . Wg2 + bg2 )
// ---------------------------------------------------------------------------
__global__ __launch_bounds__(256)
void gate_kernel(const short* __restrict__ H, const float* __restrict__ Wg2,
                 const float* __restrict__ bg2, float* __restrict__ gate)
{
    const int wid = threadIdx.x >> 6;
    const int lane = threadIdx.x & 63;
    const int row = blockIdx.x * 4 + wid;
    s16x4 hv = *(const s16x4*)&H[(size_t)row * DG_ + lane * 4];
    float4 wv = *(const float4*)&Wg2[lane * 4];
    float s = h2f(hv[0]) * wv.x + h2f(hv[1]) * wv.y + h2f(hv[2]) * wv.z + h2f(hv[3]) * wv.w;
    #pragma unroll
    for (int o = 32; o; o >>= 1) s += __shfl_down(s, o);
    if (lane == 0) gate[row] = 1.0f / (1.0f + __expf(-(s + bg2[0])));
}

// ---------------------------------------------------------------------------
// Pass A: per-chunk sums of V*cos(kp), V*sin(kp), V*cos(pp), V*sin(pp)
// ---------------------------------------------------------------------------
__global__ __launch_bounds__(256)
void passA(const short* __restrict__ V, const short* __restrict__ KP,
           const float* __restrict__ PP, f32x4* __restrict__ SI)
{
    const int bid = blockIdx.x;          // b*NC + c
    const int b = bid >> 7, c = bid & 127;
    const int d0 = threadIdx.x * 4;

    f32x4 cr = {}, ci = {}, pr = {}, pi = {};
    const size_t base  = ((size_t)b * L_ + (size_t)c * CL_) * D_ + d0;
    const size_t pbase = (size_t)c * CL_ * D_ + d0;
    for (int ll = 0; ll < CL_; ++ll) {
        s16x4 v4  = *(const s16x4*)&V [base + (size_t)ll * D_];
        s16x4 kp4 = *(const s16x4*)&KP[base + (size_t)ll * D_];
        f32x4 pp4 = *(const f32x4*)&PP[pbase + (size_t)ll * D_];
        #pragma unroll
        for (int j = 0; j < 4; ++j) {
            float v = h2f(v4[j]);
            float sk, ck, sp, cp;
            fsincos(h2f(kp4[j]), &sk, &ck);
            fsincos(pp4[j], &sp, &cp);
            cr[j] += v * ck; ci[j] += v * sk;
            pr[j] += v * cp; pi[j] += v * sp;
        }
    }
    const size_t sidx = ((size_t)bid << 10) + d0;
    #pragma unroll
    for (int j = 0; j < 4; ++j) {
        f32x4 o = { cr[j], ci[j], pr[j], pi[j] };
        SI[sidx + j] = o;
    }
}

// ---------------------------------------------------------------------------
// Pass B: in-place exclusive scan over chunks; one f32x4 per (b,c,d).
// ---------------------------------------------------------------------------
__global__ __launch_bounds__(256)
void passB(f32x4* __restrict__ SI)
{
    const int t = blockIdx.x * 256 + threadIdx.x;   // 0..B*D-1
    const int b = t >> 10, d = t & 1023;
    f32x4 run = {};
    for (int c = 0; c < NC_; ++c) {
        const size_t idx = ((size_t)(b * NC_ + c) << 10) + d;
        f32x4 v = SI[idx];
        SI[idx] = run;
        run += v;
    }
}

// ---------------------------------------------------------------------------
// Pass C: replay scan, combine with gate, /sqrt(pos), fused LayerNorm over D.
// ---------------------------------------------------------------------------
__global__ __launch_bounds__(256)
void passC(const short* __restrict__ V, const short* KP,
           const short* __restrict__ QP, const float* __restrict__ PP,
           const float* __restrict__ gate, const f32x4* __restrict__ SI,
           const float* __restrict__ ln_g, const float* __restrict__ ln_b,
           short* Yb)
{
    const int bid = blockIdx.x;
    const int b = bid >> 7, c = bid & 127;
    const int d0 = threadIdx.x * 4;

    const size_t sidx = ((size_t)bid << 10) + d0;
    f32x4 cr, ci, pr, pi;
    #pragma unroll
    for (int j = 0; j < 4; ++j) {
        f32x4 s = SI[sidx + j];
        cr[j] = s[0]; ci[j] = s[1]; pr[j] = s[2]; pi[j] = s[3];
    }
    const f32x4 g_ln = *(const f32x4*)&ln_g[d0];
    const f32x4 b_ln = *(const f32x4*)&ln_b[d0];

    __shared__ float2 lred[2][4];
    const int wid = threadIdx.x >> 6;
    const int lane = threadIdx.x & 63;

    for (int l0 = 0; l0 < CL_; ++l0) {
        const int ll = c * CL_ + l0;
        const size_t off = ((size_t)b * L_ + ll) * D_ + d0;
        s16x4 v4  = *(const s16x4*)&V [off];
        s16x4 kp4 = *(const s16x4*)&KP[off];
        s16x4 qp4 = *(const s16x4*)&QP[off];
        f32x4 pp4 = *(const f32x4*)&PP[(size_t)ll * D_ + d0];
        const float gv = gate[b * L_ + ll];
        const float rs_pos = rsqrtf((float)(ll + 1));

        f32x4 u;
        #pragma unroll
        for (int j = 0; j < 4; ++j) {
            float v = h2f(v4[j]);
            float sk, ck, sq, cq, sp, cp;
            fsincos(h2f(kp4[j]), &sk, &ck);
            fsincos(h2f(qp4[j]), &sq, &cq);
            fsincos(pp4[j], &sp, &cp);
            cr[j] += v * ck; ci[j] += v * sk;
            pr[j] += v * cp; pi[j] += v * sp;
            float content = cr[j] * cq + ci[j] * sq;
            float posr    = pr[j] * cp + pi[j] * sp;
            u[j] = (gv * content + (1.0f - gv) * posr) * rs_pos;
        }

        float s  = u[0] + u[1] + u[2] + u[3];
        float s2 = u[0]*u[0] + u[1]*u[1] + u[2]*u[2] + u[3]*u[3];
        #pragma unroll
        for (int o = 32; o; o >>= 1) {
            s  += __shfl_down(s, o);
            s2 += __shfl_down(s2, o);
        }
        const int pb = l0 & 1;
        if (lane == 0) lred[pb][wid] = make_float2(s, s2);
        __syncthreads();
        float ts  = lred[pb][0].x + lred[pb][1].x + lred[pb][2].x + lred[pb][3].x;
        float ts2 = lred[pb][0].y + lred[pb][1].y + lred[pb][2].y + lred[pb][3].y;
        const float mu  = ts * (1.0f / D_);
        const float var = ts2 * (1.0f / D_) - mu * mu;
        const float rsv = rsqrtf(var + LN_EPS_F);
        s16x4 yo;
        #pragma unroll
        for (int j = 0; j < 4; ++j)
            yo[j] = f2h((u[j] - mu) * rsv * g_ln[j] + b_ln[j]);
        *(s16x4*)&Yb[off] = yo;
    }
}

// ---------------------------------------------------------------------------
extern "C" void kernel_launch(void* const* d_in, const int* in_sizes, int n_in,
                              void* d_out, int out_size, void* d_ws, size_t ws_size,
                              hipStream_t stream)
{
    const float* x    = (const float*)d_in[0];
    const float* Wk   = (const float*)d_in[1];
    const float* bk   = (const float*)d_in[2];
    const float* Wq   = (const float*)d_in[3];
    const float* bq   = (const float*)d_in[4];
    const float* Wv   = (const float*)d_in[5];
    const float* bv   = (const float*)d_in[6];
    const float* ln_g = (const float*)d_in[7];
    const float* ln_b = (const float*)d_in[8];
    const float* Wo   = (const float*)d_in[9];
    const float* bo   = (const float*)d_in[10];
    const float* Wg1  = (const float*)d_in[11];
    const float* bg1  = (const float*)d_in[12];
    const float* Wg2  = (const float*)d_in[13];
    const float* bg2  = (const float*)d_in[14];
    const float* PP   = (const float*)d_in[15];

    float* out = (float*)d_out;

    const size_t BLD   = (size_t)B_ * L_ * D_;           // 16,777,216
    const size_t SZ_X  = BLD * 2;                        // 33,554,432
    const size_t SZ_R1 = (size_t)B_ * L_ * DG_ * 2;      //  8,388,608 (>= Wcat 6.29MB)
    const size_t SZ_G1 = (size_t)D_ * DG_ * 2;           //    524,288
    const size_t NEED  = SZ_X + SZ_R1 + SZ_G1 + 3 * SZ_X;  // 143,130,624
    if (ws_size < NEED) {
        hipMemcpyAsync(d_out, d_in[0], BLD * sizeof(float),
                       hipMemcpyDeviceToDevice, stream);
        return;
    }

    char* wsb = (char*)d_ws;
    short* xh   = (short*)(wsb);                          // region0: fp16 x
    char*  r1   = wsb + SZ_X;                             // region1: Wcat then H
    short* Wcat = (short*)r1;                             // [3072][1024] fp16
    short* H    = (short*)r1;                             // [16384][256] fp16 (after QKV GEMM)
    short* Wg1T = (short*)(r1 + SZ_R1);                   // [256][1024] fp16
    short* KP   = (short*)(r1 + SZ_R1 + SZ_G1);
    short* QP   = (short*)((char*)KP + SZ_X);
    short* V    = (short*)((char*)QP + SZ_X);
    // aliases into region0 (xh dead after H GEMM):
    float* gate = (float*)(wsb);                          // 64 KB
    short* WtO  = (short*)(wsb + 65536);                  // 2 MB
    f32x4* SI   = (f32x4*)(wsb + 65536 + 2097152);        // 8 MB interleaved scans
    short* Yb   = KP;                                     // passC writes over KP

    const int M = B_ * L_;
    dim3 blk(256);

    // 1. conversions (x and QKV weights; Wo deferred — its space is live xh)
    conv_x<<<(int)(BLD / 8 / 256), blk, 0, stream>>>(x, xh, (int)(BLD / 8));
    dim3 gT(D_ / 64, 16);
    dim3 gTg(DG_ / 64, 16);
    convT<<<gT, blk, 0, stream>>>(Wk, Wcat + 0 * D_ * D_, D_);
    convT<<<gT, blk, 0, stream>>>(Wq, Wcat + 1 * D_ * D_, D_);
    convT<<<gT, blk, 0, stream>>>(Wv, Wcat + 2 * D_ * D_, D_);
    convT<<<gTg, blk, 0, stream>>>(Wg1, Wg1T, DG_);

    // 2. fused QKV GEMM (256² pipelined), then H GEMM (overwrites dead Wcat)
    dim3 gQKV(M / 256, 3072 / 256);
    dim3 gH(M / 128, DG_ / 128);
    hipLaunchKernelGGL((mgemm256<4, short>), gQKV, dim3(512), 131072, stream,
                       xh, Wcat, nullptr, KP, QP, V, bk, bq, bv, M, 3072, D_);
    hipLaunchKernelGGL((mgemm<2>), gH, blk, 0, stream,
                       xh, Wg1T, H, bg1, M, DG_, D_);

    // 3. gate + deferred Wo conversion (xh dead now)
    gate_kernel<<<M / 4, blk, 0, stream>>>(H, Wg2, bg2, gate);
    convT<<<gT, blk, 0, stream>>>(Wo, WtO, D_);

    // 4. scans + fused LN
    passA<<<B_ * NC_, blk, 0, stream>>>(V, KP, PP, SI);
    passB<<<(B_ * D_) / 256, blk, 0, stream>>>(SI);
    passC<<<B_ * NC_, blk, 0, stream>>>(V, KP, QP, PP, gate, SI, ln_g, ln_b, Yb);

    // 5. output GEMM (+ residual), 256² pipelined
    dim3 gO(M / 256, D_ / 256);
    hipLaunchKernelGGL((mgemm256<3, float>), gO, dim3(512), 131072, stream,
                       Yb, WtO, x, out, nullptr, nullptr, bo, nullptr, nullptr,
                       M, D_, D_);
}

// Round 7
// 326.105 us; speedup vs baseline: 6.5588x; 1.0070x over previous
//
#include <hip/hip_runtime.h>
#include <math.h>

#define B_ 4
#define L_ 4096
#define D_ 1024
#define DG_ 256
#define NC_ 128         // number of chunks along L
#define CL_ 32          // chunk length (L_/NC_)
#define PI_F 3.14159265358979323846f
#define LN_EPS_F 1e-5f

typedef __attribute__((ext_vector_type(8))) _Float16 f16x8;
typedef __attribute__((ext_vector_type(8))) short s16x8;
typedef __attribute__((ext_vector_type(4))) short s16x4;
typedef __attribute__((ext_vector_type(4))) float f32x4;

__device__ inline short f2h(float f) { return __builtin_bit_cast(short, (_Float16)f); }
__device__ inline float h2f(short s) { return (float)__builtin_bit_cast(_Float16, s); }

__device__ inline float ftanh(float x) {
    float e = __expf(2.0f * x);
    return 1.0f - 2.0f / (e + 1.0f);
}
__device__ inline void fsincos(float x, float* s, float* c) {
    *s = __sinf(x); *c = __cosf(x);
}

__device__ inline void gld16(const void* g, void* l) {
    __builtin_amdgcn_global_load_lds(
        (const __attribute__((address_space(1))) unsigned int*)g,
        (__attribute__((address_space(3))) unsigned int*)l, 16, 0, 0);
}

// ---------------------------------------------------------------------------
// conv_x: fp32 -> fp16, 8 elems/thread
// ---------------------------------------------------------------------------
__global__ __launch_bounds__(256)
void conv_x(const float* __restrict__ x, short* __restrict__ xh, int n8)
{
    int t = blockIdx.x * 256 + threadIdx.x;
    if (t >= n8) return;
    const float4* p = (const float4*)x + (size_t)t * 2;
    float4 a = p[0], b = p[1];
    s16x8 v;
    v[0] = f2h(a.x); v[1] = f2h(a.y); v[2] = f2h(a.z); v[3] = f2h(a.w);
    v[4] = f2h(b.x); v[5] = f2h(b.y); v[6] = f2h(b.z); v[7] = f2h(b.w);
    *(s16x8*)(xh + (size_t)t * 8) = v;
}

// ---------------------------------------------------------------------------
// convT: W[1024][N] fp32 -> Th[N][1024] fp16, LDS-tiled transpose
// ---------------------------------------------------------------------------
__global__ __launch_bounds__(256)
void convT(const float* __restrict__ W, short* __restrict__ Th, int N)
{
    __shared__ float tile[64][65];
    const int n0 = blockIdx.x * 64, k0 = blockIdx.y * 64;
    const int t = threadIdx.x;
    const int r = t >> 4, c4 = (t & 15) * 4;

    #pragma unroll
    for (int i = 0; i < 4; ++i) {
        float4 v = *(const float4*)&W[(size_t)(k0 + r + i * 16) * N + n0 + c4];
        tile[r + i * 16][c4 + 0] = v.x;
        tile[r + i * 16][c4 + 1] = v.y;
        tile[r + i * 16][c4 + 2] = v.z;
        tile[r + i * 16][c4 + 3] = v.w;
    }
    __syncthreads();
    #pragma unroll
    for (int i = 0; i < 4; ++i) {
        const int n = r + i * 16;
        s16x4 o;
        o[0] = f2h(tile[c4 + 0][n]);
        o[1] = f2h(tile[c4 + 1][n]);
        o[2] = f2h(tile[c4 + 2][n]);
        o[3] = f2h(tile[c4 + 3][n]);
        *(s16x4*)&Th[(size_t)(n0 + n) * 1024 + k0 + c4] = o;
    }
}

// ---------------------------------------------------------------------------
// 256x256 deep-pipelined MFMA fp16 GEMM v2. BK=64, 8 waves (2Mx4N), 512 thr.
// 2 phases/K-tile (32 MFMA each); 2-K-tile unrolled loop (compile-time buffer
// offsets, ds_read = base reg + imm); strength-reduced staging pointers;
// counted vmcnt(2) at tile boundaries (never drains in steady state).
// LDS 128KB double-buffered; row-XOR swizzle (read side) + inverse-swizzled
// global source (global_load_lds writes linearly).
// EPI: 3 = +X residual -> fp32 out0
//      4 = fused QKV: bn<1024 tanh*pi->out0, <2048 tanh*pi->out1, else ->out2
// ---------------------------------------------------------------------------
#define SBAR() __builtin_amdgcn_sched_barrier(0)
#define BARRIER() do { SBAR(); __builtin_amdgcn_s_barrier(); SBAR(); } while (0)
#define LDH(P, IMM) (*(const f16x8*)((P) + (IMM)))

#define RD_AF(BASEIMM)                                                  \
    _Pragma("unroll") for (int i_ = 0; i_ < 4; ++i_) {                  \
        af[i_][0] = LDH(Ak0, (BASEIMM) + i_ * 2048);                    \
        af[i_][1] = LDH(Ak1, (BASEIMM) + i_ * 2048);                    \
    }
#define RD_BQ(BASEIMM)                                                  \
    _Pragma("unroll") for (int n_ = 0; n_ < 4; ++n_) {                  \
        bq[n_][0] = LDH(Bk0, (BASEIMM) + n_ * 2048);                    \
        bq[n_][1] = LDH(Bk1, (BASEIMM) + n_ * 2048);                    \
    }
#define MFMAS(MG)                                                       \
    _Pragma("unroll") for (int i_ = 0; i_ < 4; ++i_)                    \
    _Pragma("unroll") for (int n_ = 0; n_ < 4; ++n_)                    \
    _Pragma("unroll") for (int kk_ = 0; kk_ < 2; ++kk_)                 \
        acc[(MG) * 4 + i_][n_] = __builtin_amdgcn_mfma_f32_16x16x32_f16(\
            af[i_][kk_], bq[n_][kk_], acc[(MG) * 4 + i_][n_], 0, 0, 0);

template<int EPI, typename OT>
__global__ __launch_bounds__(512, 2)
void mgemm256(const short* __restrict__ A, const short* __restrict__ Bt,
              const float* __restrict__ X, OT* __restrict__ out0,
              short* __restrict__ out1, short* __restrict__ out2,
              const float* __restrict__ b0, const float* __restrict__ b1,
              const float* __restrict__ b2, int M, int N, int K)
{
    extern __shared__ char lds[];   // 131072: buf0/buf1 x (A 32KB + B 32KB)

    const int tid = threadIdx.x;
    const int w = tid >> 6, l = tid & 63;
    const int wr = w >> 2, wc = w & 3;          // 2 x 4 wave grid
    const int fr = l & 15, kb = l >> 4;
    const int bm = blockIdx.x * 256, bn = blockIdx.y * 256;
    const int np = K >> 7;                      // K-tile pairs

    // ---- swizzled LDS read base pointers (loop-invariant) ----
    // swizzle XOR term depends only on fr&7 (quadrant rows are 0 mod 8)
    const int s = fr & 7;
    const int cK0 = (((s >> 2) & 1) << 6) | (((kb ^ s) & 3) << 4);
    const char* Ak0 = lds + (wr << 14) + fr * 128 + cK0;
    const char* Ak1 = lds + (wr << 14) + fr * 128 + (cK0 ^ 64);
    const char* Bk0 = lds + 32768 + ((wc >> 1) << 14) + ((wc & 1) * 64 + fr) * 128 + cK0;
    const char* Bk1 = lds + 32768 + ((wc >> 1) << 14) + ((wc & 1) * 64 + fr) * 128 + (cK0 ^ 64);

    // ---- staging geometry: 8KB stream regions; per-tile advance = 64 elems
    const int p0 = tid * 16;
    const int sr = p0 >> 7;                       // row within 64-row region
    const int sc = (p0 & 127) ^ ((sr & 7) << 4);  // inverse-swizzled src col (bytes)
    const short* gA = A  + (size_t)(bm + sr) * K + (sc >> 1);
    const short* gB = Bt + (size_t)(bn + sr) * K + (sc >> 1);
    char* ldst = lds + (w << 10);                 // wave-uniform LDS dst base
    const size_t q1 = (size_t)64 * K, q2 = 2 * q1, q3 = 3 * q1;  // stream strides

    f32x4 acc[8][4] = {};
    f16x8 af[4][2];     // A frags, current mg quadrant
    f16x8 bq[4][2];     // B frags, whole tile (read once in P0)

    // ---- prologue: tile0 (8 gld) + tile1 A-fronts (2 gld) ----
    gld16(gA,       ldst);
    gld16(gA + q1,  ldst + 8192);
    gld16(gA + q2,  ldst + 16384);
    gld16(gA + q3,  ldst + 24576);
    gld16(gB,       ldst + 32768);
    gld16(gB + q1,  ldst + 40960);
    gld16(gB + q2,  ldst + 49152);
    gld16(gB + q3,  ldst + 57344);
    gld16(gA +      64, ldst + 65536);
    gld16(gA + q2 + 64, ldst + 65536 + 16384);
    asm volatile("s_waitcnt vmcnt(2)" ::: "memory");
    BARRIER();

    const short* gA1 = gA + 64;     // t+1 column pointer
    const short* gB1 = gB + 64;

    for (int pp = 0; pp < np; ++pp) {
        const bool nl = (pp + 1 < np);

        // ============ even tile (buf0) ============
        // P0: af-mg0 + all bq; stage odd-tile A-backs + B01
        RD_AF(0); RD_BQ(0);
        gld16(gA1 + q1, ldst + 65536 + 8192);
        gld16(gA1 + q3, ldst + 65536 + 24576);
        gld16(gB1,      ldst + 65536 + 32768);
        gld16(gB1 + q1, ldst + 65536 + 40960);
        BARRIER();
        __builtin_amdgcn_s_setprio(1); MFMAS(0); __builtin_amdgcn_s_setprio(0);
        BARRIER();
        // P1: af-mg1; stage odd-tile B23 + next-even A-fronts (into buf0)
        RD_AF(8192);
        gld16(gB1 + q2, ldst + 65536 + 49152);
        gld16(gB1 + q3, ldst + 65536 + 57344);
        if (nl) {
            gld16(gA1 +      64, ldst);
            gld16(gA1 + q2 + 64, ldst + 16384);
        }
        BARRIER();
        __builtin_amdgcn_s_setprio(1); MFMAS(1); __builtin_amdgcn_s_setprio(0);
        SBAR();
        if (nl) asm volatile("s_waitcnt vmcnt(2)" ::: "memory");
        else    asm volatile("s_waitcnt vmcnt(0)" ::: "memory");
        __builtin_amdgcn_s_barrier(); SBAR();

        // ============ odd tile (buf1) ============
        // P0: af-mg0 + bq from buf1; stage next-even A-backs + B01 (into buf0)
        RD_AF(65536); RD_BQ(65536);
        if (nl) {
            gld16(gA1 + q1 + 64, ldst + 8192);
            gld16(gA1 + q3 + 64, ldst + 24576);
            gld16(gB1 +      64, ldst + 32768);
            gld16(gB1 + q1 + 64, ldst + 40960);
        }
        BARRIER();
        __builtin_amdgcn_s_setprio(1); MFMAS(0); __builtin_amdgcn_s_setprio(0);
        BARRIER();
        // P1: af-mg1; stage next-even B23 + next-odd A-fronts (into buf1)
        RD_AF(65536 + 8192);
        if (nl) {
            gld16(gB1 + q2 + 64, ldst + 49152);
            gld16(gB1 + q3 + 64, ldst + 57344);
            gld16(gA1 +      128, ldst + 65536);
            gld16(gA1 + q2 + 128, ldst + 65536 + 16384);
        }
        BARRIER();
        __builtin_amdgcn_s_setprio(1); MFMAS(1); __builtin_amdgcn_s_setprio(0);
        SBAR();
        if (nl) {
            asm volatile("s_waitcnt vmcnt(2)" ::: "memory");
            __builtin_amdgcn_s_barrier(); SBAR();
        }
        gA1 += 128; gB1 += 128;
    }

    // ---- epilogue: C/D layout col=lane&15, row=(lane>>4)*4+reg ------------
    if constexpr (EPI == 4) {
        short* op; const float* bp; bool dt;
        if (bn < 1024)      { op = (short*)out0; bp = b0; dt = true;  }
        else if (bn < 2048) { op = out1;         bp = b1; dt = true;  }
        else                { op = out2;         bp = b2; dt = false; }
        const int cb = bn & 1023;
        #pragma unroll
        for (int nf = 0; nf < 4; ++nf) {
            const int cc = cb + wc * 64 + nf * 16 + fr;
            const float bcol = bp[cc];
            #pragma unroll
            for (int mf = 0; mf < 8; ++mf)
                #pragma unroll
                for (int rr = 0; rr < 4; ++rr) {
                    const int row = bm + wr * 128 + mf * 16 + kb * 4 + rr;
                    float c = acc[mf][nf][rr] + bcol;
                    if (dt) c = ftanh(c) * PI_F;
                    op[(size_t)row * 1024 + cc] = f2h(c);
                }
        }
    } else {   // EPI == 3: +X residual -> fp32
        #pragma unroll
        for (int nf = 0; nf < 4; ++nf) {
            const int col = bn + wc * 64 + nf * 16 + fr;
            const float bcol = b0[col];
            #pragma unroll
            for (int mf = 0; mf < 8; ++mf)
                #pragma unroll
                for (int rr = 0; rr < 4; ++rr) {
                    const int row = bm + wr * 128 + mf * 16 + kb * 4 + rr;
                    float c = acc[mf][nf][rr] + bcol + X[(size_t)row * N + col];
                    ((float*)out0)[(size_t)row * N + col] = c;
                }
        }
    }
}

// ---------------------------------------------------------------------------
// 128x128 MFMA GEMM (m97 structure) — used for the small H GEMM (N=256).
// EPI: 2 = gelu -> fp16
// ---------------------------------------------------------------------------
template<int EPI>
__global__ __launch_bounds__(256)
void mgemm(const short* __restrict__ A, const short* __restrict__ Bt,
           short* __restrict__ out0, const float* __restrict__ b0,
           int M, int N, int K)
{
    __shared__ __align__(16) short As[128 * 32];
    __shared__ __align__(16) short Bs[128 * 32];

    const int tid = threadIdx.x;
    const int w  = tid >> 6, l = tid & 63;
    const int wr = w >> 1,  wc = w & 1;
    const int fr = l & 15,  kb = l >> 4;
    const int bm = blockIdx.x * 128, bn = blockIdx.y * 128;

    const int srow = l >> 2;
    const int scol = (l & 3) * 8;
    const short* gA0 = A  + (size_t)(bm + w * 32 +  0 + srow) * K + scol;
    const short* gA1 = A  + (size_t)(bm + w * 32 + 16 + srow) * K + scol;
    const short* gB0 = Bt + (size_t)(bn + w * 32 +  0 + srow) * K + scol;
    const short* gB1 = Bt + (size_t)(bn + w * 32 + 16 + srow) * K + scol;
    short* lA0 = &As[(w * 32 +  0) * 32];
    short* lA1 = &As[(w * 32 + 16) * 32];
    short* lB0 = &Bs[(w * 32 +  0) * 32];
    short* lB1 = &Bs[(w * 32 + 16) * 32];

    f32x4 acc[4][4] = {};

    for (int k0 = 0; k0 < K; k0 += 32) {
        gld16(gA0 + k0, lA0); gld16(gA1 + k0, lA1);
        gld16(gB0 + k0, lB0); gld16(gB1 + k0, lB1);
        __syncthreads();

        f16x8 afr[4], bfr[4];
        #pragma unroll
        for (int m = 0; m < 4; ++m)
            afr[m] = *(const f16x8*)&As[(wr * 64 + m * 16 + fr) * 32 + kb * 8];
        #pragma unroll
        for (int n = 0; n < 4; ++n)
            bfr[n] = *(const f16x8*)&Bs[(wc * 64 + n * 16 + fr) * 32 + kb * 8];
        #pragma unroll
        for (int m = 0; m < 4; ++m)
            #pragma unroll
            for (int n = 0; n < 4; ++n)
                acc[m][n] = __builtin_amdgcn_mfma_f32_16x16x32_f16(afr[m], bfr[n], acc[m][n], 0, 0, 0);
        __syncthreads();
    }

    #pragma unroll
    for (int n = 0; n < 4; ++n) {
        const int col = bn + wc * 64 + n * 16 + fr;
        const float bcol = b0[col];
        #pragma unroll
        for (int m = 0; m < 4; ++m)
            #pragma unroll
            for (int r = 0; r < 4; ++r) {
                const int row = bm + wr * 64 + m * 16 + kb * 4 + r;
                float c = acc[m][n][r] + bcol;
                float tt = 0.7978845608028654f * (c + 0.044715f * c * c * c);
                c = 0.5f * c * (1.0f + ftanh(tt));
                out0[(size_t)row * N + col] = f2h(c);
            }
    }
}

// ---------------------------------------------------------------------------
// gate[row] = sigmoid( H[row,:] . Wg2 + bg2 )
// ---------------------------------------------------------------------------
__global__ __launch_bounds__(256)
void gate_kernel(const short* __restrict__ H, const float* __restrict__ Wg2,
                 const float* __restrict__ bg2, float* __restrict__ gate)
{
    const int wid = threadIdx.x >> 6;
    const int lane = threadIdx.x & 63;
    const int row = blockIdx.x * 4 + wid;
    s16x4 hv = *(const s16x4*)&H[(size_t)row * DG_ + lane * 4];
    float4 wv = *(const float4*)&Wg2[lane * 4];
    float s = h2f(hv[0]) * wv.x + h2f(hv[1]) * wv.y + h2f(hv[2]) * wv.z + h2f(hv[3]) * wv.w;
    #pragma unroll
    for (int o = 32; o; o >>= 1) s += __shfl_down(s, o);
    if (lane == 0) gate[row] = 1.0f / (1.0f + __expf(-(s + bg2[0])));
}

// ---------------------------------------------------------------------------
// Pass A: per-chunk sums of V*cos(kp), V*sin(kp), V*cos(pp), V*sin(pp)
// ---------------------------------------------------------------------------
__global__ __launch_bounds__(256)
void passA(const short* __restrict__ V, const short* __restrict__ KP,
           const float* __restrict__ PP, f32x4* __restrict__ SI)
{
    const int bid = blockIdx.x;          // b*NC + c
    const int b = bid >> 7, c = bid & 127;
    const int d0 = threadIdx.x * 4;

    f32x4 cr = {}, ci = {}, pr = {}, pi = {};
    const size_t base  = ((size_t)b * L_ + (size_t)c * CL_) * D_ + d0;
    const size_t pbase = (size_t)c * CL_ * D_ + d0;
    for (int ll = 0; ll < CL_; ++ll) {
        s16x4 v4  = *(const s16x4*)&V [base + (size_t)ll * D_];
        s16x4 kp4 = *(const s16x4*)&KP[base + (size_t)ll * D_];
        f32x4 pp4 = *(const f32x4*)&PP[pbase + (size_t)ll * D_];
        #pragma unroll
        for (int j = 0; j < 4; ++j) {
            float v = h2f(v4[j]);
            float sk, ck, sp, cp;
            fsincos(h2f(kp4[j]), &sk, &ck);
            fsincos(pp4[j], &sp, &cp);
            cr[j] += v * ck; ci[j] += v * sk;
            pr[j] += v * cp; pi[j] += v * sp;
        }
    }
    const size_t sidx = ((size_t)bid << 10) + d0;
    #pragma unroll
    for (int j = 0; j < 4; ++j) {
        f32x4 o = { cr[j], ci[j], pr[j], pi[j] };
        SI[sidx + j] = o;
    }
}

// ---------------------------------------------------------------------------
// Pass B: in-place exclusive scan over chunks; one f32x4 per (b,c,d).
// ---------------------------------------------------------------------------
__global__ __launch_bounds__(256)
void passB(f32x4* __restrict__ SI)
{
    const int t = blockIdx.x * 256 + threadIdx.x;   // 0..B*D-1
    const int b = t >> 10, d = t & 1023;
    f32x4 run = {};
    for (int c = 0; c < NC_; ++c) {
        const size_t idx = ((size_t)(b * NC_ + c) << 10) + d;
        f32x4 v = SI[idx];
        SI[idx] = run;
        run += v;
    }
}

// ---------------------------------------------------------------------------
// Pass C: replay scan, combine with gate, /sqrt(pos), fused LayerNorm over D.
// ---------------------------------------------------------------------------
__global__ __launch_bounds__(256)
void passC(const short* __restrict__ V, const short* KP,
           const short* __restrict__ QP, const float* __restrict__ PP,
           const float* __restrict__ gate, const f32x4* __restrict__ SI,
           const float* __restrict__ ln_g, const float* __restrict__ ln_b,
           short* Yb)
{
    const int bid = blockIdx.x;
    const int b = bid >> 7, c = bid & 127;
    const int d0 = threadIdx.x * 4;

    const size_t sidx = ((size_t)bid << 10) + d0;
    f32x4 cr, ci, pr, pi;
    #pragma unroll
    for (int j = 0; j < 4; ++j) {
        f32x4 s = SI[sidx + j];
        cr[j] = s[0]; ci[j] = s[1]; pr[j] = s[2]; pi[j] = s[3];
    }
    const f32x4 g_ln = *(const f32x4*)&ln_g[d0];
    const f32x4 b_ln = *(const f32x4*)&ln_b[d0];

    __shared__ float2 lred[2][4];
    const int wid = threadIdx.x >> 6;
    const int lane = threadIdx.x & 63;

    for (int l0 = 0; l0 < CL_; ++l0) {
        const int ll = c * CL_ + l0;
        const size_t off = ((size_t)b * L_ + ll) * D_ + d0;
        s16x4 v4  = *(const s16x4*)&V [off];
        s16x4 kp4 = *(const s16x4*)&KP[off];
        s16x4 qp4 = *(const s16x4*)&QP[off];
        f32x4 pp4 = *(const f32x4*)&PP[(size_t)ll * D_ + d0];
        const float gv = gate[b * L_ + ll];
        const float rs_pos = rsqrtf((float)(ll + 1));

        f32x4 u;
        #pragma unroll
        for (int j = 0; j < 4; ++j) {
            float v = h2f(v4[j]);
            float sk, ck, sq, cq, sp, cp;
            fsincos(h2f(kp4[j]), &sk, &ck);
            fsincos(h2f(qp4[j]), &sq, &cq);
            fsincos(pp4[j], &sp, &cp);
            cr[j] += v * ck; ci[j] += v * sk;
            pr[j] += v * cp; pi[j] += v * sp;
            float content = cr[j] * cq + ci[j] * sq;
            float posr    = pr[j] * cp + pi[j] * sp;
            u[j] = (gv * content + (1.0f - gv) * posr) * rs_pos;
        }

        float s  = u[0] + u[1] + u[2] + u[3];
        float s2 = u[0]*u[0] + u[1]*u[1] + u[2]*u[2] + u[3]*u[3];
        #pragma unroll
        for (int o = 32; o; o >>= 1) {
            s  += __shfl_down(s, o);
            s2 += __shfl_down(s2, o);
        }
        const int pb = l0 & 1;
        if (lane == 0) lred[pb][wid] = make_float2(s, s2);
        __syncthreads();
        float ts  = lred[pb][0].x + lred[pb][1].x + lred[pb][2].x + lred[pb][3].x;
        float ts2 = lred[pb][0].y + lred[pb][1].y + lred[pb][2].y + lred[pb][3].y;
        const float mu  = ts * (1.0f / D_);
        const float var = ts2 * (1.0f / D_) - mu * mu;
        const float rsv = rsqrtf(var + LN_EPS_F);
        s16x4 yo;
        #pragma unroll
        for (int j = 0; j < 4; ++j)
            yo[j] = f2h((u[j] - mu) * rsv * g_ln[j] + b_ln[j]);
        *(s16x4*)&Yb[off] = yo;
    }
}

// ---------------------------------------------------------------------------
extern "C" void kernel_launch(void* const* d_in, const int* in_sizes, int n_in,
                              void* d_out, int out_size, void* d_ws, size_t ws_size,
                              hipStream_t stream)
{
    const float* x    = (const float*)d_in[0];
    const float* Wk   = (const float*)d_in[1];
    const float* bk   = (const float*)d_in[2];
    const float* Wq   = (const float*)d_in[3];
    const float* bq   = (const float*)d_in[4];
    const float* Wv   = (const float*)d_in[5];
    const float* bv   = (const float*)d_in[6];
    const float* ln_g = (const float*)d_in[7];
    const float* ln_b = (const float*)d_in[8];
    const float* Wo   = (const float*)d_in[9];
    const float* bo   = (const float*)d_in[10];
    const float* Wg1  = (const float*)d_in[11];
    const float* bg1  = (const float*)d_in[12];
    const float* Wg2  = (const float*)d_in[13];
    const float* bg2  = (const float*)d_in[14];
    const float* PP   = (const float*)d_in[15];

    float* out = (float*)d_out;

    const size_t BLD   = (size_t)B_ * L_ * D_;           // 16,777,216
    const size_t SZ_X  = BLD * 2;                        // 33,554,432
    const size_t SZ_R1 = (size_t)B_ * L_ * DG_ * 2;      //  8,388,608 (>= Wcat 6.29MB)
    const size_t SZ_G1 = (size_t)D_ * DG_ * 2;           //    524,288
    const size_t NEED  = SZ_X + SZ_R1 + SZ_G1 + 3 * SZ_X;  // 143,130,624
    if (ws_size < NEED) {
        hipMemcpyAsync(d_out, d_in[0], BLD * sizeof(float),
                       hipMemcpyDeviceToDevice, stream);
        return;
    }

    char* wsb = (char*)d_ws;
    short* xh   = (short*)(wsb);                          // region0: fp16 x
    char*  r1   = wsb + SZ_X;                             // region1: Wcat then H
    short* Wcat = (short*)r1;                             // [3072][1024] fp16
    short* H    = (short*)r1;                             // [16384][256] fp16 (after QKV GEMM)
    short* Wg1T = (short*)(r1 + SZ_R1);                   // [256][1024] fp16
    short* KP   = (short*)(r1 + SZ_R1 + SZ_G1);
    short* QP   = (short*)((char*)KP + SZ_X);
    short* V    = (short*)((char*)QP + SZ_X);
    // aliases into region0 (xh dead after H GEMM):
    float* gate = (float*)(wsb);                          // 64 KB
    short* WtO  = (short*)(wsb + 65536);                  // 2 MB
    f32x4* SI   = (f32x4*)(wsb + 65536 + 2097152);        // 8 MB interleaved scans
    short* Yb   = KP;                                     // passC writes over KP

    const int M = B_ * L_;
    dim3 blk(256);

    // 1. conversions (x and QKV weights; Wo deferred — its space is live xh)
    conv_x<<<(int)(BLD / 8 / 256), blk, 0, stream>>>(x, xh, (int)(BLD / 8));
    dim3 gT(D_ / 64, 16);
    dim3 gTg(DG_ / 64, 16);
    convT<<<gT, blk, 0, stream>>>(Wk, Wcat + 0 * D_ * D_, D_);
    convT<<<gT, blk, 0, stream>>>(Wq, Wcat + 1 * D_ * D_, D_);
    convT<<<gT, blk, 0, stream>>>(Wv, Wcat + 2 * D_ * D_, D_);
    convT<<<gTg, blk, 0, stream>>>(Wg1, Wg1T, DG_);

    // 2. fused QKV GEMM (256² pipelined v2), then H GEMM (overwrites dead Wcat)
    dim3 gQKV(M / 256, 3072 / 256);
    dim3 gH(M / 128, DG_ / 128);
    hipLaunchKernelGGL((mgemm256<4, short>), gQKV, dim3(512), 131072, stream,
                       xh, Wcat, nullptr, KP, QP, V, bk, bq, bv, M, 3072, D_);
    hipLaunchKernelGGL((mgemm<2>), gH, blk, 0, stream,
                       xh, Wg1T, H, bg1, M, DG_, D_);

    // 3. gate + deferred Wo conversion (xh dead now)
    gate_kernel<<<M / 4, blk, 0, stream>>>(H, Wg2, bg2, gate);
    convT<<<gT, blk, 0, stream>>>(Wo, WtO, D_);

    // 4. scans + fused LN
    passA<<<B_ * NC_, blk, 0, stream>>>(V, KP, PP, SI);
    passB<<<(B_ * D_) / 256, blk, 0, stream>>>(SI);
    passC<<<B_ * NC_, blk, 0, stream>>>(V, KP, QP, PP, gate, SI, ln_g, ln_b, Yb);

    // 5. output GEMM (+ residual), 256² pipelined v2
    dim3 gO(M / 256, D_ / 256);
    hipLaunchKernelGGL((mgemm256<3, float>), gO, dim3(512), 131072, stream,
                       Yb, WtO, x, out, nullptr, nullptr, bo, nullptr, nullptr,
                       M, D_, D_);
}

// Round 8
// 323.145 us; speedup vs baseline: 6.6188x; 1.0092x over previous
//
#include <hip/hip_runtime.h>
#include <math.h>

#define B_ 4
#define L_ 4096
#define D_ 1024
#define DG_ 256
#define NC_ 128         // number of chunks along L
#define CL_ 32          // chunk length (L_/NC_)
#define PI_F 3.14159265358979323846f
#define LN_EPS_F 1e-5f

typedef __attribute__((ext_vector_type(8))) _Float16 f16x8;
typedef __attribute__((ext_vector_type(8))) short s16x8;
typedef __attribute__((ext_vector_type(4))) short s16x4;
typedef __attribute__((ext_vector_type(4))) float f32x4;

__device__ inline short f2h(float f) { return __builtin_bit_cast(short, (_Float16)f); }
__device__ inline float h2f(short s) { return (float)__builtin_bit_cast(_Float16, s); }

__device__ inline float ftanh(float x) {
    float e = __expf(2.0f * x);
    return 1.0f - 2.0f / (e + 1.0f);
}
__device__ inline void fsincos(float x, float* s, float* c) {
    *s = __sinf(x); *c = __cosf(x);
}

__device__ inline void gld16(const void* g, void* l) {
    __builtin_amdgcn_global_load_lds(
        (const __attribute__((address_space(1))) unsigned int*)g,
        (__attribute__((address_space(3))) unsigned int*)l, 16, 0, 0);
}

// ---------------------------------------------------------------------------
// conv_x: fp32 -> fp16, 8 elems/thread
// ---------------------------------------------------------------------------
__global__ __launch_bounds__(256)
void conv_x(const float* __restrict__ x, short* __restrict__ xh, int n8)
{
    int t = blockIdx.x * 256 + threadIdx.x;
    if (t >= n8) return;
    const float4* p = (const float4*)x + (size_t)t * 2;
    float4 a = p[0], b = p[1];
    s16x8 v;
    v[0] = f2h(a.x); v[1] = f2h(a.y); v[2] = f2h(a.z); v[3] = f2h(a.w);
    v[4] = f2h(b.x); v[5] = f2h(b.y); v[6] = f2h(b.z); v[7] = f2h(b.w);
    *(s16x8*)(xh + (size_t)t * 8) = v;
}

// ---------------------------------------------------------------------------
// convT: W[1024][N] fp32 -> Th[N][1024] fp16, LDS-tiled transpose
// ---------------------------------------------------------------------------
__global__ __launch_bounds__(256)
void convT(const float* __restrict__ W, short* __restrict__ Th, int N)
{
    __shared__ float tile[64][65];
    const int n0 = blockIdx.x * 64, k0 = blockIdx.y * 64;
    const int t = threadIdx.x;
    const int r = t >> 4, c4 = (t & 15) * 4;

    #pragma unroll
    for (int i = 0; i < 4; ++i) {
        float4 v = *(const float4*)&W[(size_t)(k0 + r + i * 16) * N + n0 + c4];
        tile[r + i * 16][c4 + 0] = v.x;
        tile[r + i * 16][c4 + 1] = v.y;
        tile[r + i * 16][c4 + 2] = v.z;
        tile[r + i * 16][c4 + 3] = v.w;
    }
    __syncthreads();
    #pragma unroll
    for (int i = 0; i < 4; ++i) {
        const int n = r + i * 16;
        s16x4 o;
        o[0] = f2h(tile[c4 + 0][n]);
        o[1] = f2h(tile[c4 + 1][n]);
        o[2] = f2h(tile[c4 + 2][n]);
        o[3] = f2h(tile[c4 + 3][n]);
        *(s16x4*)&Th[(size_t)(n0 + n) * 1024 + k0 + c4] = o;
    }
}

// ---------------------------------------------------------------------------
// 256x256 MFMA fp16 GEMM v3 — 8-phase schedule (4 phases per BK=64 K-tile,
// 16 MFMA per phase). Per phase: {<=8 ds_read_b128; <=4 global_load_lds;
// barrier; setprio(1); 16 MFMA; setprio(0); barrier}. The small per-phase
// LDS batch hides inside the previous phase's MFMA drain (wave-skew).
// Staging: B(t+1) in P0, A-backs(t+1) in P1, A-fronts(t+2) in P3 (into the
// region of the CURRENT buffer whose last reader finished at P1);
// one counted vmcnt(2) per tile boundary.
// LDS 128KB double-buffered; row-XOR swizzled reads + inverse-swizzled
// global source (global_load_lds writes linearly).
// EPI: 3 = +X residual -> fp32; 4 = fused QKV (tanh*pi / tanh*pi / plain)
// ---------------------------------------------------------------------------
#define SBAR() __builtin_amdgcn_sched_barrier(0)
#define BARRIER() do { SBAR(); __builtin_amdgcn_s_barrier(); SBAR(); } while (0)
#define PRIO1() __builtin_amdgcn_s_setprio(1)
#define PRIO0() __builtin_amdgcn_s_setprio(0)
#define LDH(P, IMM) (*(const f16x8*)((P) + (IMM)))

#define RD_A(KK, BASE)                                                   \
    _Pragma("unroll") for (int i_ = 0; i_ < 4; ++i_)                     \
        af[i_] = LDH((KK) ? Ak1 : Ak0, (BASE) + i_ * 2048);
#define RD_B(KK, BASE)                                                   \
    _Pragma("unroll") for (int n_ = 0; n_ < 4; ++n_)                     \
        bq[n_][KK] = LDH((KK) ? Bk1 : Bk0, (BASE) + n_ * 2048);
#define MF(MG, KK)                                                       \
    _Pragma("unroll") for (int i_ = 0; i_ < 4; ++i_)                     \
    _Pragma("unroll") for (int n_ = 0; n_ < 4; ++n_)                     \
        acc[(MG)*4 + i_][n_] = __builtin_amdgcn_mfma_f32_16x16x32_f16(   \
            af[i_], bq[n_][KK], acc[(MG)*4 + i_][n_], 0, 0, 0);

template<int EPI, typename OT>
__global__ __launch_bounds__(512, 2)
void mgemm256(const short* __restrict__ A, const short* __restrict__ Bt,
              const float* __restrict__ X, OT* __restrict__ out0,
              short* __restrict__ out1, short* __restrict__ out2,
              const float* __restrict__ b0, const float* __restrict__ b1,
              const float* __restrict__ b2, int M, int N, int K)
{
    extern __shared__ char lds[];   // 131072: buf0/buf1 x (A 32KB + B 32KB)

    const int tid = threadIdx.x;
    const int w = tid >> 6, l = tid & 63;
    const int wr = w >> 2, wc = w & 3;          // 2 x 4 wave grid
    const int fr = l & 15, kb = l >> 4;
    const int bm = blockIdx.x * 256, bn = blockIdx.y * 256;
    const int np = K >> 7;                      // K-tile pairs

    // swizzled LDS read base pointers (loop-invariant)
    const int s = fr & 7;
    const int cK0 = (((s >> 2) & 1) << 6) | (((kb ^ s) & 3) << 4);
    const char* Ak0 = lds + (wr << 14) + fr * 128 + cK0;
    const char* Ak1 = lds + (wr << 14) + fr * 128 + (cK0 ^ 64);
    const char* Bk0 = lds + 32768 + ((wc >> 1) << 14) + ((wc & 1) * 64 + fr) * 128 + cK0;
    const char* Bk1 = lds + 32768 + ((wc >> 1) << 14) + ((wc & 1) * 64 + fr) * 128 + (cK0 ^ 64);

    // staging geometry: 8KB regions; per-tile column advance = 64 elems
    const int p0 = tid * 16;
    const int sr = p0 >> 7;                       // row within 64-row region
    const int sc = (p0 & 127) ^ ((sr & 7) << 4);  // inverse-swizzled src col (bytes)
    const short* gA = A  + (size_t)(bm + sr) * K + (sc >> 1);
    const short* gB = Bt + (size_t)(bn + sr) * K + (sc >> 1);
    char* ldst = lds + (w << 10);                 // wave-uniform LDS dst base
    const size_t q1 = (size_t)64 * K, q2 = 2 * q1, q3 = 3 * q1;

    f32x4 acc[8][4] = {};
    f16x8 af[4];        // A frags, current (mg, kk)
    f16x8 bq[4][2];     // B frags, both k-halves, held across the tile

    // ---- prologue: tile0 complete + tile1 A-fronts ----
    gld16(gA,      ldst);          gld16(gA + q1, ldst + 8192);
    gld16(gA + q2, ldst + 16384);  gld16(gA + q3, ldst + 24576);
    gld16(gB,      ldst + 32768);  gld16(gB + q1, ldst + 40960);
    gld16(gB + q2, ldst + 49152);  gld16(gB + q3, ldst + 57344);
    gld16(gA +      64, ldst + 65536);
    gld16(gA + q2 + 64, ldst + 65536 + 16384);
    asm volatile("s_waitcnt vmcnt(2)" ::: "memory");
    BARRIER();

    const short* gAn = gA + 64;     // tile (2p+1) column base
    const short* gBn = gB + 64;

    for (int pp = 0; pp < np; ++pp) {
        const bool nl = (pp + 1 < np);

        // ================= even tile (cur=buf0, nxt=buf1) =================
        // P0: ds af(mg0,k0)+bq(k0); stage B(t+1)
        RD_A(0, 0); RD_B(0, 0);
        gld16(gBn,      ldst + 98304);         gld16(gBn + q1, ldst + 98304 + 8192);
        gld16(gBn + q2, ldst + 98304 + 16384); gld16(gBn + q3, ldst + 98304 + 24576);
        BARRIER();
        PRIO1(); MF(0, 0); PRIO0();
        BARRIER();
        // P1: ds af(mg0,k1)+bq(k1); stage A-backs(t+1)
        RD_A(1, 0); RD_B(1, 0);
        gld16(gAn + q1, ldst + 65536 + 8192);
        gld16(gAn + q3, ldst + 65536 + 24576);
        BARRIER();
        PRIO1(); MF(0, 1); PRIO0();
        BARRIER();
        // P2: ds af(mg1,k0)
        RD_A(0, 8192);
        BARRIER();
        PRIO1(); MF(1, 0); PRIO0();
        BARRIER();
        // P3: ds af(mg1,k1); stage A-fronts(t+2) into cur (dead since P1)
        RD_A(1, 8192);
        if (nl) { gld16(gAn + 64, ldst); gld16(gAn + 64 + q2, ldst + 16384); }
        BARRIER();
        PRIO1(); MF(1, 1); PRIO0();
        SBAR();
        asm volatile("s_waitcnt vmcnt(2)" ::: "memory");
        __builtin_amdgcn_s_barrier(); SBAR();

        // ================= odd tile (cur=buf1, nxt=buf0) =================
        // P0: ds; stage B(t+1)
        RD_A(0, 65536); RD_B(0, 65536);
        if (nl) {
            gld16(gBn +      64, ldst + 32768); gld16(gBn + q1 + 64, ldst + 40960);
            gld16(gBn + q2 + 64, ldst + 49152); gld16(gBn + q3 + 64, ldst + 57344);
        }
        BARRIER();
        PRIO1(); MF(0, 0); PRIO0();
        BARRIER();
        // P1: ds; stage A-backs(t+1)
        RD_A(1, 65536); RD_B(1, 65536);
        if (nl) {
            gld16(gAn + q1 + 64, ldst + 8192);
            gld16(gAn + q3 + 64, ldst + 24576);
        }
        BARRIER();
        PRIO1(); MF(0, 1); PRIO0();
        BARRIER();
        // P2: ds af(mg1,k0)  (last tile: drain backs first)
        if (!nl) asm volatile("s_waitcnt vmcnt(0)" ::: "memory");
        RD_A(0, 65536 + 8192);
        BARRIER();
        PRIO1(); MF(1, 0); PRIO0();
        BARRIER();
        // P3: ds af(mg1,k1); stage A-fronts(t+2)
        RD_A(1, 65536 + 8192);
        if (nl) { gld16(gAn + 128, ldst + 65536); gld16(gAn + 128 + q2, ldst + 65536 + 16384); }
        BARRIER();
        PRIO1(); MF(1, 1); PRIO0();
        SBAR();
        if (nl) {
            asm volatile("s_waitcnt vmcnt(2)" ::: "memory");
            __builtin_amdgcn_s_barrier(); SBAR();
        }
        gAn += 128; gBn += 128;
    }

    // ---- epilogue: C/D layout col=lane&15, row=(lane>>4)*4+reg ------------
    if constexpr (EPI == 4) {
        short* op; const float* bp; bool dt;
        if (bn < 1024)      { op = (short*)out0; bp = b0; dt = true;  }
        else if (bn < 2048) { op = out1;         bp = b1; dt = true;  }
        else                { op = out2;         bp = b2; dt = false; }
        const int cb = bn & 1023;
        #pragma unroll
        for (int nf = 0; nf < 4; ++nf) {
            const int cc = cb + wc * 64 + nf * 16 + fr;
            const float bcol = bp[cc];
            #pragma unroll
            for (int mf = 0; mf < 8; ++mf)
                #pragma unroll
                for (int rr = 0; rr < 4; ++rr) {
                    const int row = bm + wr * 128 + mf * 16 + kb * 4 + rr;
                    float c = acc[mf][nf][rr] + bcol;
                    if (dt) c = ftanh(c) * PI_F;
                    op[(size_t)row * 1024 + cc] = f2h(c);
                }
        }
    } else {   // EPI == 3: +X residual -> fp32
        #pragma unroll
        for (int nf = 0; nf < 4; ++nf) {
            const int col = bn + wc * 64 + nf * 16 + fr;
            const float bcol = b0[col];
            #pragma unroll
            for (int mf = 0; mf < 8; ++mf)
                #pragma unroll
                for (int rr = 0; rr < 4; ++rr) {
                    const int row = bm + wr * 128 + mf * 16 + kb * 4 + rr;
                    float c = acc[mf][nf][rr] + bcol + X[(size_t)row * N + col];
                    ((float*)out0)[(size_t)row * N + col] = c;
                }
        }
    }
}

// ---------------------------------------------------------------------------
// 128x128 MFMA GEMM (m97 structure) — small H GEMM (N=256). EPI: gelu->fp16
// ---------------------------------------------------------------------------
template<int EPI>
__global__ __launch_bounds__(256)
void mgemm(const short* __restrict__ A, const short* __restrict__ Bt,
           short* __restrict__ out0, const float* __restrict__ b0,
           int M, int N, int K)
{
    __shared__ __align__(16) short As[128 * 32];
    __shared__ __align__(16) short Bs[128 * 32];

    const int tid = threadIdx.x;
    const int w  = tid >> 6, l = tid & 63;
    const int wr = w >> 1,  wc = w & 1;
    const int fr = l & 15,  kb = l >> 4;
    const int bm = blockIdx.x * 128, bn = blockIdx.y * 128;

    const int srow = l >> 2;
    const int scol = (l & 3) * 8;
    const short* gA0 = A  + (size_t)(bm + w * 32 +  0 + srow) * K + scol;
    const short* gA1 = A  + (size_t)(bm + w * 32 + 16 + srow) * K + scol;
    const short* gB0 = Bt + (size_t)(bn + w * 32 +  0 + srow) * K + scol;
    const short* gB1 = Bt + (size_t)(bn + w * 32 + 16 + srow) * K + scol;
    short* lA0 = &As[(w * 32 +  0) * 32];
    short* lA1 = &As[(w * 32 + 16) * 32];
    short* lB0 = &Bs[(w * 32 +  0) * 32];
    short* lB1 = &Bs[(w * 32 + 16) * 32];

    f32x4 acc[4][4] = {};

    for (int k0 = 0; k0 < K; k0 += 32) {
        gld16(gA0 + k0, lA0); gld16(gA1 + k0, lA1);
        gld16(gB0 + k0, lB0); gld16(gB1 + k0, lB1);
        __syncthreads();

        f16x8 afr[4], bfr[4];
        #pragma unroll
        for (int m = 0; m < 4; ++m)
            afr[m] = *(const f16x8*)&As[(wr * 64 + m * 16 + fr) * 32 + kb * 8];
        #pragma unroll
        for (int n = 0; n < 4; ++n)
            bfr[n] = *(const f16x8*)&Bs[(wc * 64 + n * 16 + fr) * 32 + kb * 8];
        #pragma unroll
        for (int m = 0; m < 4; ++m)
            #pragma unroll
            for (int n = 0; n < 4; ++n)
                acc[m][n] = __builtin_amdgcn_mfma_f32_16x16x32_f16(afr[m], bfr[n], acc[m][n], 0, 0, 0);
        __syncthreads();
    }

    #pragma unroll
    for (int n = 0; n < 4; ++n) {
        const int col = bn + wc * 64 + n * 16 + fr;
        const float bcol = b0[col];
        #pragma unroll
        for (int m = 0; m < 4; ++m)
            #pragma unroll
            for (int r = 0; r < 4; ++r) {
                const int row = bm + wr * 64 + m * 16 + kb * 4 + r;
                float c = acc[m][n][r] + bcol;
                float tt = 0.7978845608028654f * (c + 0.044715f * c * c * c);
                c = 0.5f * c * (1.0f + ftanh(tt));
                out0[(size_t)row * N + col] = f2h(c);
            }
    }
}

// ---------------------------------------------------------------------------
// gate[row] = sigmoid( H[row,:] . Wg2 + bg2 )
// ---------------------------------------------------------------------------
__global__ __launch_bounds__(256)
void gate_kernel(const short* __restrict__ H, const float* __restrict__ Wg2,
                 const float* __restrict__ bg2, float* __restrict__ gate)
{
    const int wid = threadIdx.x >> 6;
    const int lane = threadIdx.x & 63;
    const int row = blockIdx.x * 4 + wid;
    s16x4 hv = *(const s16x4*)&H[(size_t)row * DG_ + lane * 4];
    float4 wv = *(const float4*)&Wg2[lane * 4];
    float s = h2f(hv[0]) * wv.x + h2f(hv[1]) * wv.y + h2f(hv[2]) * wv.z + h2f(hv[3]) * wv.w;
    #pragma unroll
    for (int o = 32; o; o >>= 1) s += __shfl_down(s, o);
    if (lane == 0) gate[row] = 1.0f / (1.0f + __expf(-(s + bg2[0])));
}

// ---------------------------------------------------------------------------
// Pass A: per-chunk sums of V*cos(kp), V*sin(kp), V*cos(pp), V*sin(pp)
// ---------------------------------------------------------------------------
__global__ __launch_bounds__(256)
void passA(const short* __restrict__ V, const short* __restrict__ KP,
           const float* __restrict__ PP, f32x4* __restrict__ SI)
{
    const int bid = blockIdx.x;          // b*NC + c
    const int b = bid >> 7, c = bid & 127;
    const int d0 = threadIdx.x * 4;

    f32x4 cr = {}, ci = {}, pr = {}, pi = {};
    const size_t base  = ((size_t)b * L_ + (size_t)c * CL_) * D_ + d0;
    const size_t pbase = (size_t)c * CL_ * D_ + d0;
    for (int ll = 0; ll < CL_; ++ll) {
        s16x4 v4  = *(const s16x4*)&V [base + (size_t)ll * D_];
        s16x4 kp4 = *(const s16x4*)&KP[base + (size_t)ll * D_];
        f32x4 pp4 = *(const f32x4*)&PP[pbase + (size_t)ll * D_];
        #pragma unroll
        for (int j = 0; j < 4; ++j) {
            float v = h2f(v4[j]);
            float sk, ck, sp, cp;
            fsincos(h2f(kp4[j]), &sk, &ck);
            fsincos(pp4[j], &sp, &cp);
            cr[j] += v * ck; ci[j] += v * sk;
            pr[j] += v * cp; pi[j] += v * sp;
        }
    }
    const size_t sidx = ((size_t)bid << 10) + d0;
    #pragma unroll
    for (int j = 0; j < 4; ++j) {
        f32x4 o = { cr[j], ci[j], pr[j], pi[j] };
        SI[sidx + j] = o;
    }
}

// ---------------------------------------------------------------------------
// Pass B: in-place exclusive scan over chunks; one f32x4 per (b,c,d).
// ---------------------------------------------------------------------------
__global__ __launch_bounds__(256)
void passB(f32x4* __restrict__ SI)
{
    const int t = blockIdx.x * 256 + threadIdx.x;   // 0..B*D-1
    const int b = t >> 10, d = t & 1023;
    f32x4 run = {};
    for (int c = 0; c < NC_; ++c) {
        const size_t idx = ((size_t)(b * NC_ + c) << 10) + d;
        f32x4 v = SI[idx];
        SI[idx] = run;
        run += v;
    }
}

// ---------------------------------------------------------------------------
// Pass C: replay scan, combine with gate, /sqrt(pos), fused LayerNorm over D.
// ---------------------------------------------------------------------------
__global__ __launch_bounds__(256)
void passC(const short* __restrict__ V, const short* KP,
           const short* __restrict__ QP, const float* __restrict__ PP,
           const float* __restrict__ gate, const f32x4* __restrict__ SI,
           const float* __restrict__ ln_g, const float* __restrict__ ln_b,
           short* Yb)
{
    const int bid = blockIdx.x;
    const int b = bid >> 7, c = bid & 127;
    const int d0 = threadIdx.x * 4;

    const size_t sidx = ((size_t)bid << 10) + d0;
    f32x4 cr, ci, pr, pi;
    #pragma unroll
    for (int j = 0; j < 4; ++j) {
        f32x4 s = SI[sidx + j];
        cr[j] = s[0]; ci[j] = s[1]; pr[j] = s[2]; pi[j] = s[3];
    }
    const f32x4 g_ln = *(const f32x4*)&ln_g[d0];
    const f32x4 b_ln = *(const f32x4*)&ln_b[d0];

    __shared__ float2 lred[2][4];
    const int wid = threadIdx.x >> 6;
    const int lane = threadIdx.x & 63;

    for (int l0 = 0; l0 < CL_; ++l0) {
        const int ll = c * CL_ + l0;
        const size_t off = ((size_t)b * L_ + ll) * D_ + d0;
        s16x4 v4  = *(const s16x4*)&V [off];
        s16x4 kp4 = *(const s16x4*)&KP[off];
        s16x4 qp4 = *(const s16x4*)&QP[off];
        f32x4 pp4 = *(const f32x4*)&PP[(size_t)ll * D_ + d0];
        const float gv = gate[b * L_ + ll];
        const float rs_pos = rsqrtf((float)(ll + 1));

        f32x4 u;
        #pragma unroll
        for (int j = 0; j < 4; ++j) {
            float v = h2f(v4[j]);
            float sk, ck, sq, cq, sp, cp;
            fsincos(h2f(kp4[j]), &sk, &ck);
            fsincos(h2f(qp4[j]), &sq, &cq);
            fsincos(pp4[j], &sp, &cp);
            cr[j] += v * ck; ci[j] += v * sk;
            pr[j] += v * cp; pi[j] += v * sp;
            float content = cr[j] * cq + ci[j] * sq;
            float posr    = pr[j] * cp + pi[j] * sp;
            u[j] = (gv * content + (1.0f - gv) * posr) * rs_pos;
        }

        float s  = u[0] + u[1] + u[2] + u[3];
        float s2 = u[0]*u[0] + u[1]*u[1] + u[2]*u[2] + u[3]*u[3];
        #pragma unroll
        for (int o = 32; o; o >>= 1) {
            s  += __shfl_down(s, o);
            s2 += __shfl_down(s2, o);
        }
        const int pb = l0 & 1;
        if (lane == 0) lred[pb][wid] = make_float2(s, s2);
        __syncthreads();
        float ts  = lred[pb][0].x + lred[pb][1].x + lred[pb][2].x + lred[pb][3].x;
        float ts2 = lred[pb][0].y + lred[pb][1].y + lred[pb][2].y + lred[pb][3].y;
        const float mu  = ts * (1.0f / D_);
        const float var = ts2 * (1.0f / D_) - mu * mu;
        const float rsv = rsqrtf(var + LN_EPS_F);
        s16x4 yo;
        #pragma unroll
        for (int j = 0; j < 4; ++j)
            yo[j] = f2h((u[j] - mu) * rsv * g_ln[j] + b_ln[j]);
        *(s16x4*)&Yb[off] = yo;
    }
}

// ---------------------------------------------------------------------------
extern "C" void kernel_launch(void* const* d_in, const int* in_sizes, int n_in,
                              void* d_out, int out_size, void* d_ws, size_t ws_size,
                              hipStream_t stream)
{
    const float* x    = (const float*)d_in[0];
    const float* Wk   = (const float*)d_in[1];
    const float* bk   = (const float*)d_in[2];
    const float* Wq   = (const float*)d_in[3];
    const float* bq   = (const float*)d_in[4];
    const float* Wv   = (const float*)d_in[5];
    const float* bv   = (const float*)d_in[6];
    const float* ln_g = (const float*)d_in[7];
    const float* ln_b = (const float*)d_in[8];
    const float* Wo   = (const float*)d_in[9];
    const float* bo   = (const float*)d_in[10];
    const float* Wg1  = (const float*)d_in[11];
    const float* bg1  = (const float*)d_in[12];
    const float* Wg2  = (const float*)d_in[13];
    const float* bg2  = (const float*)d_in[14];
    const float* PP   = (const float*)d_in[15];

    float* out = (float*)d_out;

    const size_t BLD   = (size_t)B_ * L_ * D_;           // 16,777,216
    const size_t SZ_X  = BLD * 2;                        // 33,554,432
    const size_t SZ_R1 = (size_t)B_ * L_ * DG_ * 2;      //  8,388,608 (>= Wcat 6.29MB)
    const size_t SZ_G1 = (size_t)D_ * DG_ * 2;           //    524,288
    const size_t NEED  = SZ_X + SZ_R1 + SZ_G1 + 3 * SZ_X;  // 143,130,624
    if (ws_size < NEED) {
        hipMemcpyAsync(d_out, d_in[0], BLD * sizeof(float),
                       hipMemcpyDeviceToDevice, stream);
        return;
    }

    char* wsb = (char*)d_ws;
    short* xh   = (short*)(wsb);                          // region0: fp16 x
    char*  r1   = wsb + SZ_X;                             // region1: Wcat then H
    short* Wcat = (short*)r1;                             // [3072][1024] fp16
    short* H    = (short*)r1;                             // [16384][256] fp16 (after QKV GEMM)
    short* Wg1T = (short*)(r1 + SZ_R1);                   // [256][1024] fp16
    short* KP   = (short*)(r1 + SZ_R1 + SZ_G1);
    short* QP   = (short*)((char*)KP + SZ_X);
    short* V    = (short*)((char*)QP + SZ_X);
    // aliases into region0 (xh dead after H GEMM):
    float* gate = (float*)(wsb);                          // 64 KB
    short* WtO  = (short*)(wsb + 65536);                  // 2 MB
    f32x4* SI   = (f32x4*)(wsb + 65536 + 2097152);        // 8 MB interleaved scans
    short* Yb   = KP;                                     // passC writes over KP

    const int M = B_ * L_;
    dim3 blk(256);

    // 1. conversions (x and QKV weights; Wo deferred — its space is live xh)
    conv_x<<<(int)(BLD / 8 / 256), blk, 0, stream>>>(x, xh, (int)(BLD / 8));
    dim3 gT(D_ / 64, 16);
    dim3 gTg(DG_ / 64, 16);
    convT<<<gT, blk, 0, stream>>>(Wk, Wcat + 0 * D_ * D_, D_);
    convT<<<gT, blk, 0, stream>>>(Wq, Wcat + 1 * D_ * D_, D_);
    convT<<<gT, blk, 0, stream>>>(Wv, Wcat + 2 * D_ * D_, D_);
    convT<<<gTg, blk, 0, stream>>>(Wg1, Wg1T, DG_);

    // 2. fused QKV GEMM (256² 8-phase), then H GEMM (overwrites dead Wcat)
    dim3 gQKV(M / 256, 3072 / 256);
    dim3 gH(M / 128, DG_ / 128);
    hipLaunchKernelGGL((mgemm256<4, short>), gQKV, dim3(512), 131072, stream,
                       xh, Wcat, nullptr, KP, QP, V, bk, bq, bv, M, 3072, D_);
    hipLaunchKernelGGL((mgemm<2>), gH, blk, 0, stream,
                       xh, Wg1T, H, bg1, M, DG_, D_);

    // 3. gate + deferred Wo conversion (xh dead now)
    gate_kernel<<<M / 4, blk, 0, stream>>>(H, Wg2, bg2, gate);
    convT<<<gT, blk, 0, stream>>>(Wo, WtO, D_);

    // 4. scans + fused LN
    passA<<<B_ * NC_, blk, 0, stream>>>(V, KP, PP, SI);
    passB<<<(B_ * D_) / 256, blk, 0, stream>>>(SI);
    passC<<<B_ * NC_, blk, 0, stream>>>(V, KP, QP, PP, gate, SI, ln_g, ln_b, Yb);

    // 5. output GEMM (+ residual), 256² 8-phase
    dim3 gO(M / 256, D_ / 256);
    hipLaunchKernelGGL((mgemm256<3, float>), gO, dim3(512), 131072, stream,
                       Yb, WtO, x, out, nullptr, nullptr, bo, nullptr, nullptr,
                       M, D_, D_);
}

// Round 9
// 301.576 us; speedup vs baseline: 7.0922x; 1.0715x over previous
//
#include <hip/hip_runtime.h>
#include <math.h>

#define B_ 4
#define L_ 4096
#define D_ 1024
#define DG_ 256
#define NC_ 128         // number of chunks along L
#define CL_ 32          // chunk length (L_/NC_)
#define PI_F 3.14159265358979323846f
#define LN_EPS_F 1e-5f

typedef __attribute__((ext_vector_type(8))) _Float16 f16x8;
typedef __attribute__((ext_vector_type(8))) short s16x8;
typedef __attribute__((ext_vector_type(4))) short s16x4;
typedef __attribute__((ext_vector_type(4))) float f32x4;

__device__ inline short f2h(float f) { return __builtin_bit_cast(short, (_Float16)f); }
__device__ inline float h2f(short s) { return (float)__builtin_bit_cast(_Float16, s); }

__device__ inline float ftanh(float x) {
    float e = __expf(2.0f * x);
    return 1.0f - 2.0f / (e + 1.0f);
}
__device__ inline void fsincos(float x, float* s, float* c) {
    *s = __sinf(x); *c = __cosf(x);
}

__device__ inline void gld16(const void* g, void* l) {
    __builtin_amdgcn_global_load_lds(
        (const __attribute__((address_space(1))) unsigned int*)g,
        (__attribute__((address_space(3))) unsigned int*)l, 16, 0, 0);
}

// ---------------------------------------------------------------------------
// conv_x: fp32 -> fp16, 8 elems/thread
// ---------------------------------------------------------------------------
__global__ __launch_bounds__(256)
void conv_x(const float* __restrict__ x, short* __restrict__ xh, int n8)
{
    int t = blockIdx.x * 256 + threadIdx.x;
    if (t >= n8) return;
    const float4* p = (const float4*)x + (size_t)t * 2;
    float4 a = p[0], b = p[1];
    s16x8 v;
    v[0] = f2h(a.x); v[1] = f2h(a.y); v[2] = f2h(a.z); v[3] = f2h(a.w);
    v[4] = f2h(b.x); v[5] = f2h(b.y); v[6] = f2h(b.z); v[7] = f2h(b.w);
    *(s16x8*)(xh + (size_t)t * 8) = v;
}

// ---------------------------------------------------------------------------
// convT: W[1024][N] fp32 -> Th[N][1024] fp16, LDS-tiled transpose
// ---------------------------------------------------------------------------
__global__ __launch_bounds__(256)
void convT(const float* __restrict__ W, short* __restrict__ Th, int N)
{
    __shared__ float tile[64][65];
    const int n0 = blockIdx.x * 64, k0 = blockIdx.y * 64;
    const int t = threadIdx.x;
    const int r = t >> 4, c4 = (t & 15) * 4;

    #pragma unroll
    for (int i = 0; i < 4; ++i) {
        float4 v = *(const float4*)&W[(size_t)(k0 + r + i * 16) * N + n0 + c4];
        tile[r + i * 16][c4 + 0] = v.x;
        tile[r + i * 16][c4 + 1] = v.y;
        tile[r + i * 16][c4 + 2] = v.z;
        tile[r + i * 16][c4 + 3] = v.w;
    }
    __syncthreads();
    #pragma unroll
    for (int i = 0; i < 4; ++i) {
        const int n = r + i * 16;
        s16x4 o;
        o[0] = f2h(tile[c4 + 0][n]);
        o[1] = f2h(tile[c4 + 1][n]);
        o[2] = f2h(tile[c4 + 2][n]);
        o[3] = f2h(tile[c4 + 3][n]);
        *(s16x4*)&Th[(size_t)(n0 + n) * 1024 + k0 + c4] = o;
    }
}

// ---------------------------------------------------------------------------
// 256x256 MFMA fp16 GEMM v4 — 8-phase schedule with INLINE-ASM ds_read_b128
// fragment loads (no memory operands -> compiler inserts no false-dependency
// vmcnt waits against outstanding global_load_lds) + explicit per-phase
// s_waitcnt lgkmcnt(0) + sched_barrier (rule #18).
// 4 phases per BK=64 K-tile, 16 MFMA each; per-tile counted vmcnt(2);
// LDS 128KB double-buffered; row-XOR swizzled reads, inverse-swizzled source.
// EPI: 3 = +X residual -> fp32; 4 = fused QKV (tanh*pi / tanh*pi / plain)
// ---------------------------------------------------------------------------
#define SBAR() __builtin_amdgcn_sched_barrier(0)
#define BARRIER() do { SBAR(); __builtin_amdgcn_s_barrier(); SBAR(); } while (0)
#define PRIO1() __builtin_amdgcn_s_setprio(1)
#define PRIO0() __builtin_amdgcn_s_setprio(0)
#define LGKM0() do { asm volatile("s_waitcnt lgkmcnt(0)" ::: "memory"); \
                     __builtin_amdgcn_sched_barrier(0); } while (0)

// inline-asm LDS read: 32-bit byte address reg + literal offset string
#define DSR(dst, areg, OFS)                                              \
    asm volatile("ds_read_b128 %0, %1 offset:" OFS                       \
                 : "=v"(dst) : "v"(areg))

#define RDA4(areg)                                                       \
    DSR(af[0], areg, "0");    DSR(af[1], areg, "2048");                  \
    DSR(af[2], areg, "4096"); DSR(af[3], areg, "6144");
#define RDA4H(areg)                                                      \
    DSR(af[0], areg, "8192");  DSR(af[1], areg, "10240");                \
    DSR(af[2], areg, "12288"); DSR(af[3], areg, "14336");
#define RDB4(areg, KK)                                                   \
    DSR(bq[0][KK], areg, "0");    DSR(bq[1][KK], areg, "2048");          \
    DSR(bq[2][KK], areg, "4096"); DSR(bq[3][KK], areg, "6144");

#define MF(MG, KK)                                                       \
    _Pragma("unroll") for (int i_ = 0; i_ < 4; ++i_)                     \
    _Pragma("unroll") for (int n_ = 0; n_ < 4; ++n_)                     \
        acc[(MG)*4 + i_][n_] = __builtin_amdgcn_mfma_f32_16x16x32_f16(   \
            af[i_], bq[n_][KK], acc[(MG)*4 + i_][n_], 0, 0, 0);

template<int EPI, typename OT>
__global__ __launch_bounds__(512, 2)
void mgemm256(const short* __restrict__ A, const short* __restrict__ Bt,
              const float* __restrict__ X, OT* __restrict__ out0,
              short* __restrict__ out1, short* __restrict__ out2,
              const float* __restrict__ b0, const float* __restrict__ b1,
              const float* __restrict__ b2, int M, int N, int K)
{
    extern __shared__ char lds[];   // 131072: buf0/buf1 x (A 32KB + B 32KB)

    const int tid = threadIdx.x;
    const int w = tid >> 6, l = tid & 63;
    const int wr = w >> 2, wc = w & 3;          // 2 x 4 wave grid
    const int fr = l & 15, kb = l >> 4;
    const int bm = blockIdx.x * 256, bn = blockIdx.y * 256;
    const int np = K >> 7;                      // K-tile pairs

    // swizzled LDS read addresses (32-bit LDS byte offsets, loop-invariant)
    const int s = fr & 7;
    const int cK0 = (((s >> 2) & 1) << 6) | (((kb ^ s) & 3) << 4);
    const int aA0 = (wr << 14) + fr * 128 + cK0;
    const int aA1 = aA0 ^ 64;
    const int aB0 = 32768 + ((wc >> 1) << 14) + ((wc & 1) * 64 + fr) * 128 + cK0;
    const int aB1 = aB0 ^ 64;
    const int aA0o = aA0 + 65536, aA1o = aA1 + 65536;
    const int aB0o = aB0 + 65536, aB1o = aB1 + 65536;

    // staging geometry: 8KB regions; per-tile column advance = 64 elems
    const int p0 = tid * 16;
    const int sr = p0 >> 7;                       // row within 64-row region
    const int sc = (p0 & 127) ^ ((sr & 7) << 4);  // inverse-swizzled src col (bytes)
    const short* gA = A  + (size_t)(bm + sr) * K + (sc >> 1);
    const short* gB = Bt + (size_t)(bn + sr) * K + (sc >> 1);
    char* ldst = lds + (w << 10);                 // wave-uniform LDS dst base
    const size_t q1 = (size_t)64 * K, q2 = 2 * q1, q3 = 3 * q1;

    f32x4 acc[8][4] = {};
    f16x8 af[4];        // A frags, current (mg, kk)
    f16x8 bq[4][2];     // B frags, both k-halves, held across the tile

    // ---- prologue: tile0 complete + tile1 A-fronts ----
    gld16(gA,      ldst);          gld16(gA + q1, ldst + 8192);
    gld16(gA + q2, ldst + 16384);  gld16(gA + q3, ldst + 24576);
    gld16(gB,      ldst + 32768);  gld16(gB + q1, ldst + 40960);
    gld16(gB + q2, ldst + 49152);  gld16(gB + q3, ldst + 57344);
    gld16(gA +      64, ldst + 65536);
    gld16(gA + q2 + 64, ldst + 65536 + 16384);
    asm volatile("s_waitcnt vmcnt(2)" ::: "memory");
    BARRIER();

    const short* gAn = gA + 64;     // tile (2p+1) column base
    const short* gBn = gB + 64;

    for (int pp = 0; pp < np; ++pp) {
        const bool nl = (pp + 1 < np);

        // ================= even tile (cur=buf0, nxt=buf1) =================
        // P0: af(mg0,k0)+bq(k0); stage B(t+1)
        RDA4(aA0); RDB4(aB0, 0);
        gld16(gBn,      ldst + 98304);         gld16(gBn + q1, ldst + 98304 + 8192);
        gld16(gBn + q2, ldst + 98304 + 16384); gld16(gBn + q3, ldst + 98304 + 24576);
        BARRIER();
        LGKM0();
        PRIO1(); MF(0, 0); PRIO0();
        BARRIER();
        // P1: af(mg0,k1)+bq(k1); stage A-backs(t+1)
        RDA4(aA1); RDB4(aB1, 1);
        gld16(gAn + q1, ldst + 65536 + 8192);
        gld16(gAn + q3, ldst + 65536 + 24576);
        BARRIER();
        LGKM0();
        PRIO1(); MF(0, 1); PRIO0();
        BARRIER();
        // P2: af(mg1,k0)
        RDA4H(aA0);
        BARRIER();
        LGKM0();
        PRIO1(); MF(1, 0); PRIO0();
        BARRIER();
        // P3: af(mg1,k1); stage A-fronts(t+2) into cur (dead since P1)
        RDA4H(aA1);
        if (nl) { gld16(gAn + 64, ldst); gld16(gAn + 64 + q2, ldst + 16384); }
        BARRIER();
        LGKM0();
        PRIO1(); MF(1, 1); PRIO0();
        SBAR();
        asm volatile("s_waitcnt vmcnt(2)" ::: "memory");
        __builtin_amdgcn_s_barrier(); SBAR();

        // ================= odd tile (cur=buf1, nxt=buf0) =================
        // P0: af+bq from buf1; stage B(t+1)
        RDA4(aA0o); RDB4(aB0o, 0);
        if (nl) {
            gld16(gBn +      64, ldst + 32768); gld16(gBn + q1 + 64, ldst + 40960);
            gld16(gBn + q2 + 64, ldst + 49152); gld16(gBn + q3 + 64, ldst + 57344);
        }
        BARRIER();
        LGKM0();
        PRIO1(); MF(0, 0); PRIO0();
        BARRIER();
        // P1: af+bq k1; stage A-backs(t+1)
        RDA4(aA1o); RDB4(aB1o, 1);
        if (nl) {
            gld16(gAn + q1 + 64, ldst + 8192);
            gld16(gAn + q3 + 64, ldst + 24576);
        }
        BARRIER();
        LGKM0();
        PRIO1(); MF(0, 1); PRIO0();
        BARRIER();
        // P2: af(mg1,k0)  (last tile: drain backs first)
        if (!nl) asm volatile("s_waitcnt vmcnt(0)" ::: "memory");
        RDA4H(aA0o);
        BARRIER();
        LGKM0();
        PRIO1(); MF(1, 0); PRIO0();
        BARRIER();
        // P3: af(mg1,k1); stage A-fronts(t+2)
        RDA4H(aA1o);
        if (nl) { gld16(gAn + 128, ldst + 65536); gld16(gAn + 128 + q2, ldst + 65536 + 16384); }
        BARRIER();
        LGKM0();
        PRIO1(); MF(1, 1); PRIO0();
        SBAR();
        if (nl) {
            asm volatile("s_waitcnt vmcnt(2)" ::: "memory");
            __builtin_amdgcn_s_barrier(); SBAR();
        }
        gAn += 128; gBn += 128;
    }

    // ---- epilogue: C/D layout col=lane&15, row=(lane>>4)*4+reg.
    // nf innermost: each row's 128B written back-to-back (line completion).
    if constexpr (EPI == 4) {
        short* op; const float* bp; bool dt;
        if (bn < 1024)      { op = (short*)out0; bp = b0; dt = true;  }
        else if (bn < 2048) { op = out1;         bp = b1; dt = true;  }
        else                { op = out2;         bp = b2; dt = false; }
        const int cb = bn & 1023;
        float bc[4];
        #pragma unroll
        for (int nf = 0; nf < 4; ++nf) bc[nf] = bp[cb + wc * 64 + nf * 16 + fr];
        #pragma unroll
        for (int mf = 0; mf < 8; ++mf)
            #pragma unroll
            for (int rr = 0; rr < 4; ++rr) {
                const int row = bm + wr * 128 + mf * 16 + kb * 4 + rr;
                #pragma unroll
                for (int nf = 0; nf < 4; ++nf) {
                    const int cc = cb + wc * 64 + nf * 16 + fr;
                    float c = acc[mf][nf][rr] + bc[nf];
                    if (dt) c = ftanh(c) * PI_F;
                    op[(size_t)row * 1024 + cc] = f2h(c);
                }
            }
    } else {   // EPI == 3: +X residual -> fp32
        float bc[4];
        #pragma unroll
        for (int nf = 0; nf < 4; ++nf) bc[nf] = b0[bn + wc * 64 + nf * 16 + fr];
        #pragma unroll
        for (int mf = 0; mf < 8; ++mf)
            #pragma unroll
            for (int rr = 0; rr < 4; ++rr) {
                const int row = bm + wr * 128 + mf * 16 + kb * 4 + rr;
                #pragma unroll
                for (int nf = 0; nf < 4; ++nf) {
                    const int col = bn + wc * 64 + nf * 16 + fr;
                    float c = acc[mf][nf][rr] + bc[nf] + X[(size_t)row * N + col];
                    ((float*)out0)[(size_t)row * N + col] = c;
                }
            }
    }
}

// ---------------------------------------------------------------------------
// 128x128 MFMA GEMM (m97 structure) — small H GEMM (N=256). EPI: gelu->fp16
// ---------------------------------------------------------------------------
template<int EPI>
__global__ __launch_bounds__(256)
void mgemm(const short* __restrict__ A, const short* __restrict__ Bt,
           short* __restrict__ out0, const float* __restrict__ b0,
           int M, int N, int K)
{
    __shared__ __align__(16) short As[128 * 32];
    __shared__ __align__(16) short Bs[128 * 32];

    const int tid = threadIdx.x;
    const int w  = tid >> 6, l = tid & 63;
    const int wr = w >> 1,  wc = w & 1;
    const int fr = l & 15,  kb = l >> 4;
    const int bm = blockIdx.x * 128, bn = blockIdx.y * 128;

    const int srow = l >> 2;
    const int scol = (l & 3) * 8;
    const short* gA0 = A  + (size_t)(bm + w * 32 +  0 + srow) * K + scol;
    const short* gA1 = A  + (size_t)(bm + w * 32 + 16 + srow) * K + scol;
    const short* gB0 = Bt + (size_t)(bn + w * 32 +  0 + srow) * K + scol;
    const short* gB1 = Bt + (size_t)(bn + w * 32 + 16 + srow) * K + scol;
    short* lA0 = &As[(w * 32 +  0) * 32];
    short* lA1 = &As[(w * 32 + 16) * 32];
    short* lB0 = &Bs[(w * 32 +  0) * 32];
    short* lB1 = &Bs[(w * 32 + 16) * 32];

    f32x4 acc[4][4] = {};

    for (int k0 = 0; k0 < K; k0 += 32) {
        gld16(gA0 + k0, lA0); gld16(gA1 + k0, lA1);
        gld16(gB0 + k0, lB0); gld16(gB1 + k0, lB1);
        __syncthreads();

        f16x8 afr[4], bfr[4];
        #pragma unroll
        for (int m = 0; m < 4; ++m)
            afr[m] = *(const f16x8*)&As[(wr * 64 + m * 16 + fr) * 32 + kb * 8];
        #pragma unroll
        for (int n = 0; n < 4; ++n)
            bfr[n] = *(const f16x8*)&Bs[(wc * 64 + n * 16 + fr) * 32 + kb * 8];
        #pragma unroll
        for (int m = 0; m < 4; ++m)
            #pragma unroll
            for (int n = 0; n < 4; ++n)
                acc[m][n] = __builtin_amdgcn_mfma_f32_16x16x32_f16(afr[m], bfr[n], acc[m][n], 0, 0, 0);
        __syncthreads();
    }

    #pragma unroll
    for (int n = 0; n < 4; ++n) {
        const int col = bn + wc * 64 + n * 16 + fr;
        const float bcol = b0[col];
        #pragma unroll
        for (int m = 0; m < 4; ++m)
            #pragma unroll
            for (int r = 0; r < 4; ++r) {
                const int row = bm + wr * 64 + m * 16 + kb * 4 + r;
                float c = acc[m][n][r] + bcol;
                float tt = 0.7978845608028654f * (c + 0.044715f * c * c * c);
                c = 0.5f * c * (1.0f + ftanh(tt));
                out0[(size_t)row * N + col] = f2h(c);
            }
    }
}

// ---------------------------------------------------------------------------
// gate[row] = sigmoid( H[row,:] . Wg2 + bg2 )
// ---------------------------------------------------------------------------
__global__ __launch_bounds__(256)
void gate_kernel(const short* __restrict__ H, const float* __restrict__ Wg2,
                 const float* __restrict__ bg2, float* __restrict__ gate)
{
    const int wid = threadIdx.x >> 6;
    const int lane = threadIdx.x & 63;
    const int row = blockIdx.x * 4 + wid;
    s16x4 hv = *(const s16x4*)&H[(size_t)row * DG_ + lane * 4];
    float4 wv = *(const float4*)&Wg2[lane * 4];
    float s = h2f(hv[0]) * wv.x + h2f(hv[1]) * wv.y + h2f(hv[2]) * wv.z + h2f(hv[3]) * wv.w;
    #pragma unroll
    for (int o = 32; o; o >>= 1) s += __shfl_down(s, o);
    if (lane == 0) gate[row] = 1.0f / (1.0f + __expf(-(s + bg2[0])));
}

// ---------------------------------------------------------------------------
// Pass A: per-chunk sums of V*cos(kp), V*sin(kp), V*cos(pp), V*sin(pp)
// ---------------------------------------------------------------------------
__global__ __launch_bounds__(256)
void passA(const short* __restrict__ V, const short* __restrict__ KP,
           const float* __restrict__ PP, f32x4* __restrict__ SI)
{
    const int bid = blockIdx.x;          // b*NC + c
    const int b = bid >> 7, c = bid & 127;
    const int d0 = threadIdx.x * 4;

    f32x4 cr = {}, ci = {}, pr = {}, pi = {};
    const size_t base  = ((size_t)b * L_ + (size_t)c * CL_) * D_ + d0;
    const size_t pbase = (size_t)c * CL_ * D_ + d0;
    for (int ll = 0; ll < CL_; ++ll) {
        s16x4 v4  = *(const s16x4*)&V [base + (size_t)ll * D_];
        s16x4 kp4 = *(const s16x4*)&KP[base + (size_t)ll * D_];
        f32x4 pp4 = *(const f32x4*)&PP[pbase + (size_t)ll * D_];
        #pragma unroll
        for (int j = 0; j < 4; ++j) {
            float v = h2f(v4[j]);
            float sk, ck, sp, cp;
            fsincos(h2f(kp4[j]), &sk, &ck);
            fsincos(pp4[j], &sp, &cp);
            cr[j] += v * ck; ci[j] += v * sk;
            pr[j] += v * cp; pi[j] += v * sp;
        }
    }
    const size_t sidx = ((size_t)bid << 10) + d0;
    #pragma unroll
    for (int j = 0; j < 4; ++j) {
        f32x4 o = { cr[j], ci[j], pr[j], pi[j] };
        SI[sidx + j] = o;
    }
}

// ---------------------------------------------------------------------------
// Pass B: in-place exclusive scan over chunks; one f32x4 per (b,c,d).
// ---------------------------------------------------------------------------
__global__ __launch_bounds__(256)
void passB(f32x4* __restrict__ SI)
{
    const int t = blockIdx.x * 256 + threadIdx.x;   // 0..B*D-1
    const int b = t >> 10, d = t & 1023;
    f32x4 run = {};
    for (int c = 0; c < NC_; ++c) {
        const size_t idx = ((size_t)(b * NC_ + c) << 10) + d;
        f32x4 v = SI[idx];
        SI[idx] = run;
        run += v;
    }
}

// ---------------------------------------------------------------------------
// Pass C: replay scan, combine with gate, /sqrt(pos), fused LayerNorm over D.
// ---------------------------------------------------------------------------
__global__ __launch_bounds__(256)
void passC(const short* __restrict__ V, const short* KP,
           const short* __restrict__ QP, const float* __restrict__ PP,
           const float* __restrict__ gate, const f32x4* __restrict__ SI,
           const float* __restrict__ ln_g, const float* __restrict__ ln_b,
           short* Yb)
{
    const int bid = blockIdx.x;
    const int b = bid >> 7, c = bid & 127;
    const int d0 = threadIdx.x * 4;

    const size_t sidx = ((size_t)bid << 10) + d0;
    f32x4 cr, ci, pr, pi;
    #pragma unroll
    for (int j = 0; j < 4; ++j) {
        f32x4 s = SI[sidx + j];
        cr[j] = s[0]; ci[j] = s[1]; pr[j] = s[2]; pi[j] = s[3];
    }
    const f32x4 g_ln = *(const f32x4*)&ln_g[d0];
    const f32x4 b_ln = *(const f32x4*)&ln_b[d0];

    __shared__ float2 lred[2][4];
    const int wid = threadIdx.x >> 6;
    const int lane = threadIdx.x & 63;

    for (int l0 = 0; l0 < CL_; ++l0) {
        const int ll = c * CL_ + l0;
        const size_t off = ((size_t)b * L_ + ll) * D_ + d0;
        s16x4 v4  = *(const s16x4*)&V [off];
        s16x4 kp4 = *(const s16x4*)&KP[off];
        s16x4 qp4 = *(const s16x4*)&QP[off];
        f32x4 pp4 = *(const f32x4*)&PP[(size_t)ll * D_ + d0];
        const float gv = gate[b * L_ + ll];
        const float rs_pos = rsqrtf((float)(ll + 1));

        f32x4 u;
        #pragma unroll
        for (int j = 0; j < 4; ++j) {
            float v = h2f(v4[j]);
            float sk, ck, sq, cq, sp, cp;
            fsincos(h2f(kp4[j]), &sk, &ck);
            fsincos(h2f(qp4[j]), &sq, &cq);
            fsincos(pp4[j], &sp, &cp);
            cr[j] += v * ck; ci[j] += v * sk;
            pr[j] += v * cp; pi[j] += v * sp;
            float content = cr[j] * cq + ci[j] * sq;
            float posr    = pr[j] * cp + pi[j] * sp;
            u[j] = (gv * content + (1.0f - gv) * posr) * rs_pos;
        }

        float s  = u[0] + u[1] + u[2] + u[3];
        float s2 = u[0]*u[0] + u[1]*u[1] + u[2]*u[2] + u[3]*u[3];
        #pragma unroll
        for (int o = 32; o; o >>= 1) {
            s  += __shfl_down(s, o);
            s2 += __shfl_down(s2, o);
        }
        const int pb = l0 & 1;
        if (lane == 0) lred[pb][wid] = make_float2(s, s2);
        __syncthreads();
        float ts  = lred[pb][0].x + lred[pb][1].x + lred[pb][2].x + lred[pb][3].x;
        float ts2 = lred[pb][0].y + lred[pb][1].y + lred[pb][2].y + lred[pb][3].y;
        const float mu  = ts * (1.0f / D_);
        const float var = ts2 * (1.0f / D_) - mu * mu;
        const float rsv = rsqrtf(var + LN_EPS_F);
        s16x4 yo;
        #pragma unroll
        for (int j = 0; j < 4; ++j)
            yo[j] = f2h((u[j] - mu) * rsv * g_ln[j] + b_ln[j]);
        *(s16x4*)&Yb[off] = yo;
    }
}

// ---------------------------------------------------------------------------
extern "C" void kernel_launch(void* const* d_in, const int* in_sizes, int n_in,
                              void* d_out, int out_size, void* d_ws, size_t ws_size,
                              hipStream_t stream)
{
    const float* x    = (const float*)d_in[0];
    const float* Wk   = (const float*)d_in[1];
    const float* bk   = (const float*)d_in[2];
    const float* Wq   = (const float*)d_in[3];
    const float* bq   = (const float*)d_in[4];
    const float* Wv   = (const float*)d_in[5];
    const float* bv   = (const float*)d_in[6];
    const float* ln_g = (const float*)d_in[7];
    const float* ln_b = (const float*)d_in[8];
    const float* Wo   = (const float*)d_in[9];
    const float* bo   = (const float*)d_in[10];
    const float* Wg1  = (const float*)d_in[11];
    const float* bg1  = (const float*)d_in[12];
    const float* Wg2  = (const float*)d_in[13];
    const float* bg2  = (const float*)d_in[14];
    const float* PP   = (const float*)d_in[15];

    float* out = (float*)d_out;

    const size_t BLD   = (size_t)B_ * L_ * D_;           // 16,777,216
    const size_t SZ_X  = BLD * 2;                        // 33,554,432
    const size_t SZ_R1 = (size_t)B_ * L_ * DG_ * 2;      //  8,388,608 (>= Wcat 6.29MB)
    const size_t SZ_G1 = (size_t)D_ * DG_ * 2;           //    524,288
    const size_t NEED  = SZ_X + SZ_R1 + SZ_G1 + 3 * SZ_X;  // 143,130,624
    if (ws_size < NEED) {
        hipMemcpyAsync(d_out, d_in[0], BLD * sizeof(float),
                       hipMemcpyDeviceToDevice, stream);
        return;
    }

    char* wsb = (char*)d_ws;
    short* xh   = (short*)(wsb);                          // region0: fp16 x
    char*  r1   = wsb + SZ_X;                             // region1: Wcat then H
    short* Wcat = (short*)r1;                             // [3072][1024] fp16
    short* H    = (short*)r1;                             // [16384][256] fp16 (after QKV GEMM)
    short* Wg1T = (short*)(r1 + SZ_R1);                   // [256][1024] fp16
    short* KP   = (short*)(r1 + SZ_R1 + SZ_G1);
    short* QP   = (short*)((char*)KP + SZ_X);
    short* V    = (short*)((char*)QP + SZ_X);
    // aliases into region0 (xh dead after H GEMM):
    float* gate = (float*)(wsb);                          // 64 KB
    short* WtO  = (short*)(wsb + 65536);                  // 2 MB
    f32x4* SI   = (f32x4*)(wsb + 65536 + 2097152);        // 8 MB interleaved scans
    short* Yb   = KP;                                     // passC writes over KP

    const int M = B_ * L_;
    dim3 blk(256);

    // 1. conversions (x and QKV weights; Wo deferred — its space is live xh)
    conv_x<<<(int)(BLD / 8 / 256), blk, 0, stream>>>(x, xh, (int)(BLD / 8));
    dim3 gT(D_ / 64, 16);
    dim3 gTg(DG_ / 64, 16);
    convT<<<gT, blk, 0, stream>>>(Wk, Wcat + 0 * D_ * D_, D_);
    convT<<<gT, blk, 0, stream>>>(Wq, Wcat + 1 * D_ * D_, D_);
    convT<<<gT, blk, 0, stream>>>(Wv, Wcat + 2 * D_ * D_, D_);
    convT<<<gTg, blk, 0, stream>>>(Wg1, Wg1T, DG_);

    // 2. fused QKV GEMM (256² 8-phase, asm ds_reads), then H GEMM
    dim3 gQKV(M / 256, 3072 / 256);
    dim3 gH(M / 128, DG_ / 128);
    hipLaunchKernelGGL((mgemm256<4, short>), gQKV, dim3(512), 131072, stream,
                       xh, Wcat, nullptr, KP, QP, V, bk, bq, bv, M, 3072, D_);
    hipLaunchKernelGGL((mgemm<2>), gH, blk, 0, stream,
                       xh, Wg1T, H, bg1, M, DG_, D_);

    // 3. gate + deferred Wo conversion (xh dead now)
    gate_kernel<<<M / 4, blk, 0, stream>>>(H, Wg2, bg2, gate);
    convT<<<gT, blk, 0, stream>>>(Wo, WtO, D_);

    // 4. scans + fused LN
    passA<<<B_ * NC_, blk, 0, stream>>>(V, KP, PP, SI);
    passB<<<(B_ * D_) / 256, blk, 0, stream>>>(SI);
    passC<<<B_ * NC_, blk, 0, stream>>>(V, KP, QP, PP, gate, SI, ln_g, ln_b, Yb);

    // 5. output GEMM (+ residual), 256² 8-phase
    dim3 gO(M / 256, D_ / 256);
    hipLaunchKernelGGL((mgemm256<3, float>), gO, dim3(512), 131072, stream,
                       Yb, WtO, x, out, nullptr, nullptr, bo, nullptr, nullptr,
                       M, D_, D_);
}